// Round 5
// baseline (177.457 us; speedup 1.0000x reference)
//
#include <hip/hip_runtime.h>
#include <cstddef>

#define G_N   10000
#define L_N   1000
#define NSTA  400
#define NSRC  2000
#define KK    15
#define NBIN  2048
#define CAP   1024
#define NIT   40          // ceil(G_N / 256)

__device__ __forceinline__ float tr1k(float x) {
    // matches reference: _ftrns(x)/1000.0 = (x*1000.0f)/1000.0f with f32 rounding
    return (x * 1000.0f) / 1000.0f;
}

__device__ __forceinline__ float softplus(float x) {
    // jax.nn.softplus(x) = logaddexp(x, 0), stable form
    return fmaxf(x, 0.0f) + log1pf(expf(-fabsf(x)));
}

__device__ __forceinline__ bool lexless(float v1, int i1, float v2, int i2) {
    return (v1 < v2) || (v1 == v2 && i1 < i2);
}

// ---------------------------------------------------------------------------
// Kernel 1: sta_ind[i] = argmin_j ||tr(sta[i]) - tr(locs_ref[j])||^2
// one wave per station. Also zeroes the used[] flags (runs before topk).
// ---------------------------------------------------------------------------
__global__ void sta_ind_kernel(const float* __restrict__ sta,
                               const float* __restrict__ locs_ref,
                               int* __restrict__ sta_ind,
                               int* __restrict__ used) {
#pragma clang fp contract(off)
    const int i    = blockIdx.x;
    const int lane = threadIdx.x;

    if (used) {
        int z = blockIdx.x * 64 + lane;          // 400*64 = 25600 >= G_N
        if (z < G_N) used[z] = 0;
    }

    const float sx = tr1k(sta[i * 3 + 0]);
    const float sy = tr1k(sta[i * 3 + 1]);
    const float sz = tr1k(sta[i * 3 + 2]);
    float best = INFINITY;
    int   bidx = 0x7fffffff;
    for (int j = lane; j < L_N; j += 64) {
        float dx = sx - tr1k(locs_ref[j * 3 + 0]);
        float dy = sy - tr1k(locs_ref[j * 3 + 1]);
        float dz = sz - tr1k(locs_ref[j * 3 + 2]);
        float d  = (dx * dx + dy * dy) + dz * dz;
        if (lexless(d, j, best, bidx)) { best = d; bidx = j; }
    }
    for (int off = 1; off < 64; off <<= 1) {
        float ov = __shfl_xor(best, off);
        int   oi = __shfl_xor(bidx, off);
        if (lexless(ov, oi, best, bidx)) { best = ov; bidx = oi; }
    }
    if (lane == 0) sta_ind[i] = bidx;
}

// ---------------------------------------------------------------------------
// Kernel 2 (v3): histogram select, register-resident distances.
// One block (256 thr) per src. Distances live in dreg[NIT] (static unroll).
// Phase 1: distances + 2048-bin histogram of bits>>20 (monotonic key).
// Phase 2: wave 0 prefix-scans bins -> boundary bin B (cum >= 15).
// Phase 3: append (g, d) of keys <= B (expected ~15-40) to LDS list.
// Phase 4: wave 0 lex-sorts survivors, writes 15 ascending (dq, g), marks used.
// Fallback (survivors > CAP): 15 rounds of block lex-argmin over dreg.
// ---------------------------------------------------------------------------
__global__ __launch_bounds__(256) void topk_kernel(const float* __restrict__ src,
                                                   const float* __restrict__ x_grid,
                                                   int* __restrict__ idx_out,
                                                   int* __restrict__ used) {
#pragma clang fp contract(off)
    const int s    = blockIdx.x;
    const int tid  = threadIdx.x;
    const int lane = tid & 63;
    const int wv   = tid >> 6;

    __shared__ unsigned int s_hist[NBIN];
    __shared__ int          s_cand[CAP];
    __shared__ float        s_cd[CAP];
    __shared__ int          s_cnt;
    __shared__ int          s_binB;
    __shared__ int          s_nle;
    __shared__ float        s_mv[4];
    __shared__ int          s_mi[4];

    for (int b = tid; b < NBIN; b += 256) s_hist[b] = 0u;
    if (tid == 0) s_cnt = 0;
    __syncthreads();

    const float sx = tr1k(src[s * 3 + 0]);
    const float sy = tr1k(src[s * 3 + 1]);
    const float sz = tr1k(src[s * 3 + 2]);

    float dreg[NIT];
#pragma unroll
    for (int it = 0; it < NIT; ++it) {
        const int g = tid + it * 256;
        float d = INFINITY;
        if (g < G_N) {
            float dx = sx - tr1k(x_grid[g * 3 + 0]);
            float dy = sy - tr1k(x_grid[g * 3 + 1]);
            float dz = sz - tr1k(x_grid[g * 3 + 2]);
            d = (dx * dx + dy * dy) + dz * dz;
            atomicAdd(&s_hist[__float_as_uint(d) >> 20], 1u);
        }
        dreg[it] = d;
    }
    __syncthreads();

    // wave 0: find boundary bin
    if (wv == 0) {
        const int chunk = NBIN / 64;           // 32 bins per lane
        const int base  = lane * chunk;
        unsigned int cs = 0;
        for (int b = 0; b < chunk; ++b) cs += s_hist[base + b];
        unsigned int pfx = cs;
        for (int off = 1; off < 64; off <<= 1) {
            unsigned int o = __shfl_up(pfx, off);
            if (lane >= off) pfx += o;
        }
        unsigned long long m = __ballot(pfx >= (unsigned)KK);
        int fl = __ffsll((unsigned long long)m) - 1;
        if (lane == fl) {
            unsigned int acc = pfx - cs;       // cumulative before this chunk (< KK)
            int b = base;
            for (;;) {
                acc += s_hist[b];
                if (acc >= (unsigned)KK) break;
                ++b;
            }
            s_binB = b;
            s_nle  = (int)acc;                 // count of keys <= B
        }
    }
    __syncthreads();

    const int binB = s_binB;
    const int nle  = s_nle;

    if (nle <= CAP) {
#pragma unroll
        for (int it = 0; it < NIT; ++it) {
            // OOB entries have key(INF)=2040 > binB (finite keys <= 2039)
            if ((int)(__float_as_uint(dreg[it]) >> 20) <= binB) {
                int p = atomicAdd(&s_cnt, 1);
                s_cand[p] = tid + it * 256;
                s_cd[p]   = dreg[it];
            }
        }
        __syncthreads();
        if (wv == 0) {
            const int n = s_cnt;
            float vals[KK];
            int   ids[KK];
#pragma unroll
            for (int j = 0; j < KK; ++j) { vals[j] = INFINITY; ids[j] = 0x7fffffff; }
            for (int c = lane; c < n; c += 64) {
                int   g = s_cand[c];
                float d = s_cd[c];
                if (lexless(d, g, vals[KK - 1], ids[KK - 1])) {
                    float cv = d; int ci = g;
#pragma unroll
                    for (int j = 0; j < KK; ++j) {
                        bool sw = lexless(cv, ci, vals[j], ids[j]);
                        float tv = sw ? vals[j] : cv;
                        int   ti = sw ? ids[j]  : ci;
                        vals[j]  = sw ? cv : vals[j];
                        ids[j]   = sw ? ci : ids[j];
                        cv = tv; ci = ti;
                    }
                }
            }
            for (int r = 0; r < KK; ++r) {
                float v  = vals[0];
                int   id = ids[0];
                int   who = lane;
                for (int off = 1; off < 64; off <<= 1) {
                    float ov = __shfl_xor(v, off);
                    int   oi = __shfl_xor(id, off);
                    int   ow = __shfl_xor(who, off);
                    if (lexless(ov, oi, v, id)) { v = ov; id = oi; who = ow; }
                }
                if (lane == 0) {
                    idx_out[s * KK + r] = id;
                    if (used) used[id] = 1;    // benign race; all writers store 1
                }
                if (who == lane) {
#pragma unroll
                    for (int j = 0; j < KK - 1; ++j) { vals[j] = vals[j + 1]; ids[j] = ids[j + 1]; }
                    vals[KK - 1] = INFINITY;
                    ids[KK - 1]  = 0x7fffffff;
                }
            }
        }
    } else {
        // fallback: 15 rounds of block-wide lex-argmin with removal (never expected)
        for (int r = 0; r < KK; ++r) {
            float v  = INFINITY;
            int   id = 0x7fffffff;
#pragma unroll
            for (int it = 0; it < NIT; ++it) {
                const int g = tid + it * 256;
                if (g < G_N && lexless(dreg[it], g, v, id)) { v = dreg[it]; id = g; }
            }
            for (int off = 1; off < 64; off <<= 1) {
                float ov = __shfl_xor(v, off);
                int   oi = __shfl_xor(id, off);
                if (lexless(ov, oi, v, id)) { v = ov; id = oi; }
            }
            if (lane == 0) { s_mv[wv] = v; s_mi[wv] = id; }
            __syncthreads();
            float bv = s_mv[0]; int bi = s_mi[0];
            for (int w = 1; w < 4; ++w)
                if (lexless(s_mv[w], s_mi[w], bv, bi)) { bv = s_mv[w]; bi = s_mi[w]; }
            if (tid == 0) {
                idx_out[s * KK + r] = bi;
                if (used) used[bi] = 1;
            }
#pragma unroll
            for (int it = 0; it < NIT; ++it)
                if (tid + it * 256 == bi) dreg[it] = INFINITY;
            __syncthreads();
        }
    }
}

// ---------------------------------------------------------------------------
// Kernel 3: pack. One block per used g. Stages the 12 KB ker row + 8 KB coef
// row into LDS with float4 loads (coalesced), then gathers the 400 station
// columns from LDS. Writes float4 {1/sp(k0),1/sp(k1),1/sp(k2),c_sel} [g][i].
// ---------------------------------------------------------------------------
__global__ __launch_bounds__(256) void pack_kernel(
    const float* __restrict__ coefs, const float* __restrict__ coefs_ker,
    const int* __restrict__ sta_ind, const int* __restrict__ phase,
    const int* __restrict__ used,
    float4* __restrict__ pk)
{
    const int g = blockIdx.x;
    if (!used[g]) return;            // wave-uniform early exit
    const int tid = threadIdx.x;

    __shared__ float s_ker[L_N * 3];
    __shared__ float s_c[L_N * 2];

    const float4* kr4 = (const float4*)(coefs_ker + (size_t)g * (L_N * 3)); // 750 vec4
    const float4* cr4 = (const float4*)(coefs     + (size_t)g * (L_N * 2)); // 500 vec4
    float4* sk4 = (float4*)s_ker;
    float4* sc4 = (float4*)s_c;
#pragma unroll
    for (int j = 0; j < 3; ++j) {
        int p = tid + j * 256;
        if (p < (L_N * 3) / 4) sk4[p] = kr4[p];
    }
#pragma unroll
    for (int j = 0; j < 2; ++j) {
        int p = tid + j * 256;
        if (p < (L_N * 2) / 4) sc4[p] = cr4[p];
    }
    // prefetch station gather indices (coalesced) before the barrier
    const int i1 = tid + 256;
    const int st0 = sta_ind[tid];                       // tid < 256 <= NSTA
    const int ph0 = phase[tid];
    const int st1 = (i1 < NSTA) ? sta_ind[i1] : 0;
    const int ph1 = (i1 < NSTA) ? phase[i1] : 0;
    __syncthreads();

    {
        float rk0 = 1.0f / softplus(s_ker[st0 * 3 + 0]);
        float rk1 = 1.0f / softplus(s_ker[st0 * 3 + 1]);
        float rk2 = 1.0f / softplus(s_ker[st0 * 3 + 2]);
        float c   = (ph0 == 0) ? s_c[st0 * 2 + 0] : s_c[st0 * 2 + 1];
        pk[(size_t)g * NSTA + tid] = make_float4(rk0, rk1, rk2, c);
    }
    if (i1 < NSTA) {
        float rk0 = 1.0f / softplus(s_ker[st1 * 3 + 0]);
        float rk1 = 1.0f / softplus(s_ker[st1 * 3 + 1]);
        float rk2 = 1.0f / softplus(s_ker[st1 * 3 + 2]);
        float c   = (ph1 == 0) ? s_c[st1 * 2 + 0] : s_c[st1 * 2 + 1];
        pk[(size_t)g * NSTA + i1] = make_float4(rk0, rk1, rk2, c);
    }
}

// ---------------------------------------------------------------------------
// Kernel 4: main fused computation, fast path. Block per src, coalesced
// float4 reads of the packed table.
// ---------------------------------------------------------------------------
__global__ __launch_bounds__(256) void magnitude_fast_kernel(
    const float* __restrict__ sta, const float* __restrict__ src,
    const float* __restrict__ mag, const int* __restrict__ phase,
    const float* __restrict__ x_grid,
    const float* __restrict__ mag_coef, const float* __restrict__ epi_coef,
    const float* __restrict__ dep_coef,
    const float4* __restrict__ pk, const int* __restrict__ idx,
    float* __restrict__ out)
{
    const int s   = blockIdx.x;
    const int tid = threadIdx.x;

    __shared__ float s_diff[KK][3];
    __shared__ int   s_g[KK];

    if (tid < KK) {
        int g = idx[s * KK + tid];
        s_g[tid] = g;
        s_diff[tid][0] = tr1k(x_grid[g * 3 + 0]) - tr1k(src[s * 3 + 0]);
        s_diff[tid][1] = tr1k(x_grid[g * 3 + 1]) - tr1k(src[s * 3 + 1]);
        s_diff[tid][2] = tr1k(x_grid[g * 3 + 2]) - tr1k(src[s * 3 + 2]);
    }
    __syncthreads();

    const float mag_s = mag[s];
    const float srcx = src[s * 3 + 0];
    const float srcy = src[s * 3 + 1];
    const float srcz = src[s * 3 + 2];
    const float sp_mc0 = softplus(mag_coef[0]), sp_mc1 = softplus(mag_coef[1]);
    const float sp_ec0 = softplus(epi_coef[0]), sp_ec1 = softplus(epi_coef[1]);
    const float dc0 = dep_coef[0], dc1 = dep_coef[1];

    for (int i = tid; i < NSTA; i += 256) {
        float wsum = 0.0f, a = 0.0f;
#pragma unroll
        for (int k = 0; k < KK; ++k) {
            const float4 p = pk[(size_t)s_g[k] * NSTA + i];
            float t0 = s_diff[k][0] * p.x;
            float t1 = s_diff[k][1] * p.y;
            float t2 = s_diff[k][2] * p.z;
            float e  = __expf(-0.5f * ((t0 * t0 + t1 * t1) + t2 * t2));
            wsum += e;
            a    += e * p.w;
        }
        if (wsum == 0.0f) wsum = 1.0f;

        const int ph = phase[i];
        float bias = a / wsum;

        float dx = srcx * 1000.0f - sta[i * 3 + 0] * 1000.0f;
        float dy = srcy * 1000.0f - sta[i * 3 + 1] * 1000.0f;
        float lz = log10f(sqrtf(dx * dx + dy * dy) + 1.0f);
        float ld = log10f(fabsf(srcz - sta[i * 3 + 2]) + 1.0f);

        float mc = (ph == 0) ? sp_mc0 : sp_mc1;
        float ec = (ph == 0) ? sp_ec0 : sp_ec1;
        float dc = (ph == 0) ? dc0 : dc1;

        out[(size_t)s * NSTA + i] = mag_s * mc - ec * lz + dc * ld + bias;
    }
}

// ---------------------------------------------------------------------------
// Fallback main kernel (direct gather) if ws_size can't hold the packed table.
// ---------------------------------------------------------------------------
__global__ __launch_bounds__(256) void magnitude_kernel(
    const float* __restrict__ sta, const float* __restrict__ src,
    const float* __restrict__ mag, const int* __restrict__ phase,
    const float* __restrict__ x_grid,
    const float* __restrict__ mag_coef, const float* __restrict__ epi_coef,
    const float* __restrict__ dep_coef,
    const float* __restrict__ coefs, const float* __restrict__ coefs_ker,
    const int* __restrict__ sta_ind, const int* __restrict__ idx,
    float* __restrict__ out)
{
    const int s   = blockIdx.x;
    const int tid = threadIdx.x;

    __shared__ float s_diff[KK][3];
    __shared__ int   s_g[KK];
    __shared__ int   s_sta[NSTA];

    if (tid < KK) {
        int g = idx[s * KK + tid];
        s_g[tid] = g;
        s_diff[tid][0] = tr1k(x_grid[g * 3 + 0]) - tr1k(src[s * 3 + 0]);
        s_diff[tid][1] = tr1k(x_grid[g * 3 + 1]) - tr1k(src[s * 3 + 1]);
        s_diff[tid][2] = tr1k(x_grid[g * 3 + 2]) - tr1k(src[s * 3 + 2]);
    }
    for (int i = tid; i < NSTA; i += 256) s_sta[i] = sta_ind[i];
    __syncthreads();

    const float mag_s = mag[s];
    const float srcx = src[s * 3 + 0];
    const float srcy = src[s * 3 + 1];
    const float srcz = src[s * 3 + 2];
    const float sp_mc0 = softplus(mag_coef[0]), sp_mc1 = softplus(mag_coef[1]);
    const float sp_ec0 = softplus(epi_coef[0]), sp_ec1 = softplus(epi_coef[1]);
    const float dc0 = dep_coef[0], dc1 = dep_coef[1];

    for (int i = tid; i < NSTA; i += 256) {
        const int st = s_sta[i];
        float wsum = 0.0f, a0 = 0.0f, a1 = 0.0f;
#pragma unroll
        for (int k = 0; k < KK; ++k) {
            const int g = s_g[k];
            const float* kp = coefs_ker + ((size_t)g * L_N + st) * 3;
            float k0 = softplus(kp[0]);
            float k1 = softplus(kp[1]);
            float k2 = softplus(kp[2]);
            float t0 = s_diff[k][0] / k0;
            float t1 = s_diff[k][1] / k1;
            float t2 = s_diff[k][2] / k2;
            float e  = expf(-0.5f * ((t0 * t0 + t1 * t1) + t2 * t2));
            const float* cp = coefs + ((size_t)g * L_N + st) * 2;
            wsum += e;
            a0 += e * cp[0];
            a1 += e * cp[1];
        }
        if (wsum == 0.0f) wsum = 1.0f;

        const int ph = phase[i];
        float bias = ((ph == 0) ? a0 : a1) / wsum;

        float dx = srcx * 1000.0f - sta[i * 3 + 0] * 1000.0f;
        float dy = srcy * 1000.0f - sta[i * 3 + 1] * 1000.0f;
        float lz = log10f(sqrtf(dx * dx + dy * dy) + 1.0f);
        float ld = log10f(fabsf(srcz - sta[i * 3 + 2]) + 1.0f);

        float mc = (ph == 0) ? sp_mc0 : sp_mc1;
        float ec = (ph == 0) ? sp_ec0 : sp_ec1;
        float dc = (ph == 0) ? dc0 : dc1;

        out[(size_t)s * NSTA + i] = mag_s * mc - ec * lz + dc * ld + bias;
    }
}

extern "C" void kernel_launch(void* const* d_in, const int* in_sizes, int n_in,
                              void* d_out, int out_size, void* d_ws, size_t ws_size,
                              hipStream_t stream) {
    const float* sta       = (const float*)d_in[0];
    const float* src       = (const float*)d_in[1];
    const float* mag       = (const float*)d_in[2];
    const int*   phase     = (const int*)d_in[3];
    const float* x_grid    = (const float*)d_in[4];
    const float* locs_ref  = (const float*)d_in[5];
    const float* mag_coef  = (const float*)d_in[6];
    const float* epi_coef  = (const float*)d_in[7];
    const float* dep_coef  = (const float*)d_in[8];
    const float* coefs     = (const float*)d_in[9];
    const float* coefs_ker = (const float*)d_in[10];
    float* out = (float*)d_out;

    const size_t pk_bytes = (size_t)G_N * NSTA * sizeof(float4);  // 64 MB
    const size_t need_fast = pk_bytes
                           + (size_t)NSRC * KK * sizeof(int)
                           + (size_t)NSTA * sizeof(int)
                           + (size_t)G_N * sizeof(int);

    if (ws_size >= need_fast) {
        float4* ws_pk  = (float4*)d_ws;
        int* ws_idx    = (int*)((char*)d_ws + pk_bytes);
        int* ws_sta    = ws_idx + (size_t)NSRC * KK;
        int* ws_used   = ws_sta + NSTA;

        hipLaunchKernelGGL(sta_ind_kernel, dim3(NSTA), dim3(64), 0, stream,
                           sta, locs_ref, ws_sta, ws_used);
        hipLaunchKernelGGL(topk_kernel, dim3(NSRC), dim3(256), 0, stream,
                           src, x_grid, ws_idx, ws_used);
        hipLaunchKernelGGL(pack_kernel, dim3(G_N), dim3(256), 0, stream,
                           coefs, coefs_ker, ws_sta, phase, ws_used, ws_pk);
        hipLaunchKernelGGL(magnitude_fast_kernel, dim3(NSRC), dim3(256), 0, stream,
                           sta, src, mag, phase, x_grid,
                           mag_coef, epi_coef, dep_coef,
                           ws_pk, ws_idx, out);
    } else {
        int* ws_sta = (int*)d_ws;
        int* ws_idx = ws_sta + NSTA;

        hipLaunchKernelGGL(sta_ind_kernel, dim3(NSTA), dim3(64), 0, stream,
                           sta, locs_ref, ws_sta, (int*)nullptr);
        hipLaunchKernelGGL(topk_kernel, dim3(NSRC), dim3(256), 0, stream,
                           src, x_grid, ws_idx, (int*)nullptr);
        hipLaunchKernelGGL(magnitude_kernel, dim3(NSRC), dim3(256), 0, stream,
                           sta, src, mag, phase, x_grid,
                           mag_coef, epi_coef, dep_coef,
                           coefs, coefs_ker, ws_sta, ws_idx, out);
    }
}

// Round 6
// 157.734 us; speedup vs baseline: 1.1250x; 1.1250x over previous
//
#include <hip/hip_runtime.h>
#include <cstddef>

#define G_N   10000
#define L_N   1000
#define NSTA  400
#define NSRC  2000
#define KK    15
#define NBIN  2048
#define CAP   512

__device__ __forceinline__ float tr1k(float x) {
    // matches reference: _ftrns(x)/1000.0 = (x*1000.0f)/1000.0f with f32 rounding
    return (x * 1000.0f) / 1000.0f;
}

__device__ __forceinline__ float softplus(float x) {
    // jax.nn.softplus(x) = logaddexp(x, 0), stable form
    return fmaxf(x, 0.0f) + log1pf(expf(-fabsf(x)));
}

__device__ __forceinline__ bool lexless(float v1, int i1, float v2, int i2) {
    return (v1 < v2) || (v1 == v2 && i1 < i2);
}

// ---------------------------------------------------------------------------
// Kernel 1: sta_ind[i] = argmin_j ||tr(sta[i]) - tr(locs_ref[j])||^2
// one wave per station. Also zeroes the used[] flags (runs before topk).
// ---------------------------------------------------------------------------
__global__ void sta_ind_kernel(const float* __restrict__ sta,
                               const float* __restrict__ locs_ref,
                               int* __restrict__ sta_ind,
                               int* __restrict__ used) {
#pragma clang fp contract(off)
    const int i    = blockIdx.x;
    const int lane = threadIdx.x;

    if (used) {
        int z = blockIdx.x * 64 + lane;          // 400*64 = 25600 >= G_N
        if (z < G_N) used[z] = 0;
    }

    const float sx = tr1k(sta[i * 3 + 0]);
    const float sy = tr1k(sta[i * 3 + 1]);
    const float sz = tr1k(sta[i * 3 + 2]);
    float best = INFINITY;
    int   bidx = 0x7fffffff;
    for (int j = lane; j < L_N; j += 64) {
        float dx = sx - tr1k(locs_ref[j * 3 + 0]);
        float dy = sy - tr1k(locs_ref[j * 3 + 1]);
        float dz = sz - tr1k(locs_ref[j * 3 + 2]);
        float d  = (dx * dx + dy * dy) + dz * dz;
        if (lexless(d, j, best, bidx)) { best = d; bidx = j; }
    }
    for (int off = 1; off < 64; off <<= 1) {
        float ov = __shfl_xor(best, off);
        int   oi = __shfl_xor(bidx, off);
        if (lexless(ov, oi, best, bidx)) { best = ov; bidx = oi; }
    }
    if (lane == 0) sta_ind[i] = bidx;
}

// ---------------------------------------------------------------------------
// Kernel 2 (v4): histogram select with NO distance storage.
// Pass 1: compute d, build 2048-bin histogram of bits>>20 (monotonic key).
// Wave 0: prefix-scan bins -> boundary bin B (cumulative count >= 15).
// Pass 2: recompute d (bit-identical), append (g,d) with key <= B (~17).
// Wave 0: lex-sort survivors, write 15 ascending (dq, g), mark used.
// Fallback (survivors > CAP, never expected): 15 rounds of block argmin
// with recompute + exclusion list. Correct for any data.
// ---------------------------------------------------------------------------
__global__ __launch_bounds__(256, 8) void topk_kernel(const float* __restrict__ src,
                                                      const float* __restrict__ x_grid,
                                                      int* __restrict__ idx_out,
                                                      int* __restrict__ used) {
#pragma clang fp contract(off)
    const int s    = blockIdx.x;
    const int tid  = threadIdx.x;
    const int lane = tid & 63;
    const int wv   = tid >> 6;

    __shared__ unsigned int s_hist[NBIN];   // 8 KB
    __shared__ int          s_cand[CAP];    // 2 KB
    __shared__ float        s_cd[CAP];      // 2 KB
    __shared__ int          s_cnt;
    __shared__ int          s_binB;
    __shared__ int          s_nle;
    __shared__ float        s_mv[4];
    __shared__ int          s_mi[4];
    __shared__ int          s_ch[KK];

    for (int b = tid; b < NBIN; b += 256) s_hist[b] = 0u;
    if (tid == 0) s_cnt = 0;
    __syncthreads();

    const float sx = tr1k(src[s * 3 + 0]);
    const float sy = tr1k(src[s * 3 + 1]);
    const float sz = tr1k(src[s * 3 + 2]);

    // pass 1: histogram only
    for (int g = tid; g < G_N; g += 256) {
        float dx = sx - tr1k(x_grid[g * 3 + 0]);
        float dy = sy - tr1k(x_grid[g * 3 + 1]);
        float dz = sz - tr1k(x_grid[g * 3 + 2]);
        float d  = (dx * dx + dy * dy) + dz * dz;
        atomicAdd(&s_hist[__float_as_uint(d) >> 20], 1u);
    }
    __syncthreads();

    // wave 0: find boundary bin
    if (wv == 0) {
        const int chunk = NBIN / 64;           // 32 bins per lane
        const int base  = lane * chunk;
        unsigned int cs = 0;
        for (int b = 0; b < chunk; ++b) cs += s_hist[base + b];
        unsigned int pfx = cs;
        for (int off = 1; off < 64; off <<= 1) {
            unsigned int o = __shfl_up(pfx, off);
            if (lane >= off) pfx += o;
        }
        unsigned long long m = __ballot(pfx >= (unsigned)KK);
        int fl = __ffsll((unsigned long long)m) - 1;
        if (lane == fl) {
            unsigned int acc = pfx - cs;       // cumulative before this chunk (< KK)
            int b = base;
            for (;;) {
                acc += s_hist[b];
                if (acc >= (unsigned)KK) break;
                ++b;
            }
            s_binB = b;
            s_nle  = (int)acc;                 // count of keys <= B
        }
    }
    __syncthreads();

    const int binB = s_binB;
    const int nle  = s_nle;

    if (nle <= CAP) {
        // pass 2: recompute, append survivors
        for (int g = tid; g < G_N; g += 256) {
            float dx = sx - tr1k(x_grid[g * 3 + 0]);
            float dy = sy - tr1k(x_grid[g * 3 + 1]);
            float dz = sz - tr1k(x_grid[g * 3 + 2]);
            float d  = (dx * dx + dy * dy) + dz * dz;
            if ((int)(__float_as_uint(d) >> 20) <= binB) {
                int p = atomicAdd(&s_cnt, 1);
                s_cand[p] = g;
                s_cd[p]   = d;
            }
        }
        __syncthreads();
        if (wv == 0) {
            const int n = s_cnt;
            float vals[KK];
            int   ids[KK];
#pragma unroll
            for (int j = 0; j < KK; ++j) { vals[j] = INFINITY; ids[j] = 0x7fffffff; }
            for (int c = lane; c < n; c += 64) {
                int   g = s_cand[c];
                float d = s_cd[c];
                if (lexless(d, g, vals[KK - 1], ids[KK - 1])) {
                    float cv = d; int ci = g;
#pragma unroll
                    for (int j = 0; j < KK; ++j) {
                        bool sw = lexless(cv, ci, vals[j], ids[j]);
                        float tv = sw ? vals[j] : cv;
                        int   ti = sw ? ids[j]  : ci;
                        vals[j]  = sw ? cv : vals[j];
                        ids[j]   = sw ? ci : ids[j];
                        cv = tv; ci = ti;
                    }
                }
            }
            for (int r = 0; r < KK; ++r) {
                float v  = vals[0];
                int   id = ids[0];
                int   who = lane;
                for (int off = 1; off < 64; off <<= 1) {
                    float ov = __shfl_xor(v, off);
                    int   oi = __shfl_xor(id, off);
                    int   ow = __shfl_xor(who, off);
                    if (lexless(ov, oi, v, id)) { v = ov; id = oi; who = ow; }
                }
                if (lane == 0) {
                    idx_out[s * KK + r] = id;
                    if (used) used[id] = 1;    // benign race; all writers store 1
                }
                if (who == lane) {
#pragma unroll
                    for (int j = 0; j < KK - 1; ++j) { vals[j] = vals[j + 1]; ids[j] = ids[j + 1]; }
                    vals[KK - 1] = INFINITY;
                    ids[KK - 1]  = 0x7fffffff;
                }
            }
        }
    } else {
        // slow exact fallback: 15 rounds of block argmin with recompute +
        // exclusion list (deterministic; not expected to trigger)
        for (int r = 0; r < KK; ++r) {
            float v  = INFINITY;
            int   id = 0x7fffffff;
            for (int g = tid; g < G_N; g += 256) {
                bool skip = false;
                for (int j = 0; j < r; ++j) skip = skip || (s_ch[j] == g);
                if (skip) continue;
                float dx = sx - tr1k(x_grid[g * 3 + 0]);
                float dy = sy - tr1k(x_grid[g * 3 + 1]);
                float dz = sz - tr1k(x_grid[g * 3 + 2]);
                float d  = (dx * dx + dy * dy) + dz * dz;
                if (lexless(d, g, v, id)) { v = d; id = g; }
            }
            for (int off = 1; off < 64; off <<= 1) {
                float ov = __shfl_xor(v, off);
                int   oi = __shfl_xor(id, off);
                if (lexless(ov, oi, v, id)) { v = ov; id = oi; }
            }
            if (lane == 0) { s_mv[wv] = v; s_mi[wv] = id; }
            __syncthreads();
            if (tid == 0) {
                float bv = s_mv[0]; int bi = s_mi[0];
                for (int w = 1; w < 4; ++w)
                    if (lexless(s_mv[w], s_mi[w], bv, bi)) { bv = s_mv[w]; bi = s_mi[w]; }
                s_ch[r] = bi;
                idx_out[s * KK + r] = bi;
                if (used) used[bi] = 1;
            }
            __syncthreads();
        }
    }
}

// ---------------------------------------------------------------------------
// Kernel 3: pack. One block per used g. Stages the 12 KB ker row + 8 KB coef
// row into LDS with float4 loads (coalesced), then gathers the 400 station
// columns from LDS. Writes float4 {1/sp(k0),1/sp(k1),1/sp(k2),c_sel} [g][i].
// ---------------------------------------------------------------------------
__global__ __launch_bounds__(256) void pack_kernel(
    const float* __restrict__ coefs, const float* __restrict__ coefs_ker,
    const int* __restrict__ sta_ind, const int* __restrict__ phase,
    const int* __restrict__ used,
    float4* __restrict__ pk)
{
    const int g = blockIdx.x;
    if (!used[g]) return;            // wave-uniform early exit
    const int tid = threadIdx.x;

    __shared__ float s_ker[L_N * 3];
    __shared__ float s_c[L_N * 2];

    const float4* kr4 = (const float4*)(coefs_ker + (size_t)g * (L_N * 3)); // 750 vec4
    const float4* cr4 = (const float4*)(coefs     + (size_t)g * (L_N * 2)); // 500 vec4
    float4* sk4 = (float4*)s_ker;
    float4* sc4 = (float4*)s_c;
#pragma unroll
    for (int j = 0; j < 3; ++j) {
        int p = tid + j * 256;
        if (p < (L_N * 3) / 4) sk4[p] = kr4[p];
    }
#pragma unroll
    for (int j = 0; j < 2; ++j) {
        int p = tid + j * 256;
        if (p < (L_N * 2) / 4) sc4[p] = cr4[p];
    }
    // prefetch station gather indices (coalesced) before the barrier
    const int i1 = tid + 256;
    const int st0 = sta_ind[tid];                       // tid < 256 <= NSTA
    const int ph0 = phase[tid];
    const int st1 = (i1 < NSTA) ? sta_ind[i1] : 0;
    const int ph1 = (i1 < NSTA) ? phase[i1] : 0;
    __syncthreads();

    {
        float rk0 = 1.0f / softplus(s_ker[st0 * 3 + 0]);
        float rk1 = 1.0f / softplus(s_ker[st0 * 3 + 1]);
        float rk2 = 1.0f / softplus(s_ker[st0 * 3 + 2]);
        float c   = (ph0 == 0) ? s_c[st0 * 2 + 0] : s_c[st0 * 2 + 1];
        pk[(size_t)g * NSTA + tid] = make_float4(rk0, rk1, rk2, c);
    }
    if (i1 < NSTA) {
        float rk0 = 1.0f / softplus(s_ker[st1 * 3 + 0]);
        float rk1 = 1.0f / softplus(s_ker[st1 * 3 + 1]);
        float rk2 = 1.0f / softplus(s_ker[st1 * 3 + 2]);
        float c   = (ph1 == 0) ? s_c[st1 * 2 + 0] : s_c[st1 * 2 + 1];
        pk[(size_t)g * NSTA + i1] = make_float4(rk0, rk1, rk2, c);
    }
}

// ---------------------------------------------------------------------------
// Kernel 4: main fused computation, fast path. Block per src, coalesced
// float4 reads of the packed table.
// ---------------------------------------------------------------------------
__global__ __launch_bounds__(256) void magnitude_fast_kernel(
    const float* __restrict__ sta, const float* __restrict__ src,
    const float* __restrict__ mag, const int* __restrict__ phase,
    const float* __restrict__ x_grid,
    const float* __restrict__ mag_coef, const float* __restrict__ epi_coef,
    const float* __restrict__ dep_coef,
    const float4* __restrict__ pk, const int* __restrict__ idx,
    float* __restrict__ out)
{
    const int s   = blockIdx.x;
    const int tid = threadIdx.x;

    __shared__ float s_diff[KK][3];
    __shared__ int   s_g[KK];

    if (tid < KK) {
        int g = idx[s * KK + tid];
        s_g[tid] = g;
        s_diff[tid][0] = tr1k(x_grid[g * 3 + 0]) - tr1k(src[s * 3 + 0]);
        s_diff[tid][1] = tr1k(x_grid[g * 3 + 1]) - tr1k(src[s * 3 + 1]);
        s_diff[tid][2] = tr1k(x_grid[g * 3 + 2]) - tr1k(src[s * 3 + 2]);
    }
    __syncthreads();

    const float mag_s = mag[s];
    const float srcx = src[s * 3 + 0];
    const float srcy = src[s * 3 + 1];
    const float srcz = src[s * 3 + 2];
    const float sp_mc0 = softplus(mag_coef[0]), sp_mc1 = softplus(mag_coef[1]);
    const float sp_ec0 = softplus(epi_coef[0]), sp_ec1 = softplus(epi_coef[1]);
    const float dc0 = dep_coef[0], dc1 = dep_coef[1];

    for (int i = tid; i < NSTA; i += 256) {
        float wsum = 0.0f, a = 0.0f;
#pragma unroll
        for (int k = 0; k < KK; ++k) {
            const float4 p = pk[(size_t)s_g[k] * NSTA + i];
            float t0 = s_diff[k][0] * p.x;
            float t1 = s_diff[k][1] * p.y;
            float t2 = s_diff[k][2] * p.z;
            float e  = __expf(-0.5f * ((t0 * t0 + t1 * t1) + t2 * t2));
            wsum += e;
            a    += e * p.w;
        }
        if (wsum == 0.0f) wsum = 1.0f;

        const int ph = phase[i];
        float bias = a / wsum;

        float dx = srcx * 1000.0f - sta[i * 3 + 0] * 1000.0f;
        float dy = srcy * 1000.0f - sta[i * 3 + 1] * 1000.0f;
        float lz = log10f(sqrtf(dx * dx + dy * dy) + 1.0f);
        float ld = log10f(fabsf(srcz - sta[i * 3 + 2]) + 1.0f);

        float mc = (ph == 0) ? sp_mc0 : sp_mc1;
        float ec = (ph == 0) ? sp_ec0 : sp_ec1;
        float dc = (ph == 0) ? dc0 : dc1;

        out[(size_t)s * NSTA + i] = mag_s * mc - ec * lz + dc * ld + bias;
    }
}

// ---------------------------------------------------------------------------
// Fallback main kernel (direct gather) if ws_size can't hold the packed table.
// ---------------------------------------------------------------------------
__global__ __launch_bounds__(256) void magnitude_kernel(
    const float* __restrict__ sta, const float* __restrict__ src,
    const float* __restrict__ mag, const int* __restrict__ phase,
    const float* __restrict__ x_grid,
    const float* __restrict__ mag_coef, const float* __restrict__ epi_coef,
    const float* __restrict__ dep_coef,
    const float* __restrict__ coefs, const float* __restrict__ coefs_ker,
    const int* __restrict__ sta_ind, const int* __restrict__ idx,
    float* __restrict__ out)
{
    const int s   = blockIdx.x;
    const int tid = threadIdx.x;

    __shared__ float s_diff[KK][3];
    __shared__ int   s_g[KK];
    __shared__ int   s_sta[NSTA];

    if (tid < KK) {
        int g = idx[s * KK + tid];
        s_g[tid] = g;
        s_diff[tid][0] = tr1k(x_grid[g * 3 + 0]) - tr1k(src[s * 3 + 0]);
        s_diff[tid][1] = tr1k(x_grid[g * 3 + 1]) - tr1k(src[s * 3 + 1]);
        s_diff[tid][2] = tr1k(x_grid[g * 3 + 2]) - tr1k(src[s * 3 + 2]);
    }
    for (int i = tid; i < NSTA; i += 256) s_sta[i] = sta_ind[i];
    __syncthreads();

    const float mag_s = mag[s];
    const float srcx = src[s * 3 + 0];
    const float srcy = src[s * 3 + 1];
    const float srcz = src[s * 3 + 2];
    const float sp_mc0 = softplus(mag_coef[0]), sp_mc1 = softplus(mag_coef[1]);
    const float sp_ec0 = softplus(epi_coef[0]), sp_ec1 = softplus(epi_coef[1]);
    const float dc0 = dep_coef[0], dc1 = dep_coef[1];

    for (int i = tid; i < NSTA; i += 256) {
        const int st = s_sta[i];
        float wsum = 0.0f, a0 = 0.0f, a1 = 0.0f;
#pragma unroll
        for (int k = 0; k < KK; ++k) {
            const int g = s_g[k];
            const float* kp = coefs_ker + ((size_t)g * L_N + st) * 3;
            float k0 = softplus(kp[0]);
            float k1 = softplus(kp[1]);
            float k2 = softplus(kp[2]);
            float t0 = s_diff[k][0] / k0;
            float t1 = s_diff[k][1] / k1;
            float t2 = s_diff[k][2] / k2;
            float e  = expf(-0.5f * ((t0 * t0 + t1 * t1) + t2 * t2));
            const float* cp = coefs + ((size_t)g * L_N + st) * 2;
            wsum += e;
            a0 += e * cp[0];
            a1 += e * cp[1];
        }
        if (wsum == 0.0f) wsum = 1.0f;

        const int ph = phase[i];
        float bias = ((ph == 0) ? a0 : a1) / wsum;

        float dx = srcx * 1000.0f - sta[i * 3 + 0] * 1000.0f;
        float dy = srcy * 1000.0f - sta[i * 3 + 1] * 1000.0f;
        float lz = log10f(sqrtf(dx * dx + dy * dy) + 1.0f);
        float ld = log10f(fabsf(srcz - sta[i * 3 + 2]) + 1.0f);

        float mc = (ph == 0) ? sp_mc0 : sp_mc1;
        float ec = (ph == 0) ? sp_ec0 : sp_ec1;
        float dc = (ph == 0) ? dc0 : dc1;

        out[(size_t)s * NSTA + i] = mag_s * mc - ec * lz + dc * ld + bias;
    }
}

extern "C" void kernel_launch(void* const* d_in, const int* in_sizes, int n_in,
                              void* d_out, int out_size, void* d_ws, size_t ws_size,
                              hipStream_t stream) {
    const float* sta       = (const float*)d_in[0];
    const float* src       = (const float*)d_in[1];
    const float* mag       = (const float*)d_in[2];
    const int*   phase     = (const int*)d_in[3];
    const float* x_grid    = (const float*)d_in[4];
    const float* locs_ref  = (const float*)d_in[5];
    const float* mag_coef  = (const float*)d_in[6];
    const float* epi_coef  = (const float*)d_in[7];
    const float* dep_coef  = (const float*)d_in[8];
    const float* coefs     = (const float*)d_in[9];
    const float* coefs_ker = (const float*)d_in[10];
    float* out = (float*)d_out;

    const size_t pk_bytes = (size_t)G_N * NSTA * sizeof(float4);  // 64 MB
    const size_t need_fast = pk_bytes
                           + (size_t)NSRC * KK * sizeof(int)
                           + (size_t)NSTA * sizeof(int)
                           + (size_t)G_N * sizeof(int);

    if (ws_size >= need_fast) {
        float4* ws_pk  = (float4*)d_ws;
        int* ws_idx    = (int*)((char*)d_ws + pk_bytes);
        int* ws_sta    = ws_idx + (size_t)NSRC * KK;
        int* ws_used   = ws_sta + NSTA;

        hipLaunchKernelGGL(sta_ind_kernel, dim3(NSTA), dim3(64), 0, stream,
                           sta, locs_ref, ws_sta, ws_used);
        hipLaunchKernelGGL(topk_kernel, dim3(NSRC), dim3(256), 0, stream,
                           src, x_grid, ws_idx, ws_used);
        hipLaunchKernelGGL(pack_kernel, dim3(G_N), dim3(256), 0, stream,
                           coefs, coefs_ker, ws_sta, phase, ws_used, ws_pk);
        hipLaunchKernelGGL(magnitude_fast_kernel, dim3(NSRC), dim3(256), 0, stream,
                           sta, src, mag, phase, x_grid,
                           mag_coef, epi_coef, dep_coef,
                           ws_pk, ws_idx, out);
    } else {
        int* ws_sta = (int*)d_ws;
        int* ws_idx = ws_sta + NSTA;

        hipLaunchKernelGGL(sta_ind_kernel, dim3(NSTA), dim3(64), 0, stream,
                           sta, locs_ref, ws_sta, (int*)nullptr);
        hipLaunchKernelGGL(topk_kernel, dim3(NSRC), dim3(256), 0, stream,
                           src, x_grid, ws_idx, (int*)nullptr);
        hipLaunchKernelGGL(magnitude_kernel, dim3(NSRC), dim3(256), 0, stream,
                           sta, src, mag, phase, x_grid,
                           mag_coef, epi_coef, dep_coef,
                           coefs, coefs_ker, ws_sta, ws_idx, out);
    }
}

// Round 7
// 138.431 us; speedup vs baseline: 1.2819x; 1.1394x over previous
//
#include <hip/hip_runtime.h>
#include <hip/hip_fp16.h>
#include <cstddef>

#define G_N   10000
#define L_N   1000
#define NSTA  400
#define NSRC  2000
#define KK    15
#define NBIN  2048
#define CAP   512

__device__ __forceinline__ float tr1k(float x) {
    // matches reference: _ftrns(x)/1000.0 = (x*1000.0f)/1000.0f with f32 rounding
    return (x * 1000.0f) / 1000.0f;
}

__device__ __forceinline__ float softplus(float x) {
    // jax.nn.softplus(x) = logaddexp(x, 0), stable form (accurate libm)
    return fmaxf(x, 0.0f) + log1pf(expf(-fabsf(x)));
}

__device__ __forceinline__ float softplus_fast(float x) {
    // fast-math variant: HW v_exp/v_log. |err| ~1e-6 abs, fine vs 0.2175 thr.
    return fmaxf(x, 0.0f) + __logf(1.0f + __expf(-fabsf(x)));
}

__device__ __forceinline__ bool lexless(float v1, int i1, float v2, int i2) {
    return (v1 < v2) || (v1 == v2 && i1 < i2);
}

// ---------------------------------------------------------------------------
// Kernel 1: sta_ind[i] = argmin_j ||tr(sta[i]) - tr(locs_ref[j])||^2
// one wave per station. Also zeroes the used[] flags (runs before topk).
// ---------------------------------------------------------------------------
__global__ void sta_ind_kernel(const float* __restrict__ sta,
                               const float* __restrict__ locs_ref,
                               int* __restrict__ sta_ind,
                               int* __restrict__ used) {
#pragma clang fp contract(off)
    const int i    = blockIdx.x;
    const int lane = threadIdx.x;

    if (used) {
        int z = blockIdx.x * 64 + lane;          // 400*64 = 25600 >= G_N
        if (z < G_N) used[z] = 0;
    }

    const float sx = tr1k(sta[i * 3 + 0]);
    const float sy = tr1k(sta[i * 3 + 1]);
    const float sz = tr1k(sta[i * 3 + 2]);
    float best = INFINITY;
    int   bidx = 0x7fffffff;
    for (int j = lane; j < L_N; j += 64) {
        float dx = sx - tr1k(locs_ref[j * 3 + 0]);
        float dy = sy - tr1k(locs_ref[j * 3 + 1]);
        float dz = sz - tr1k(locs_ref[j * 3 + 2]);
        float d  = (dx * dx + dy * dy) + dz * dz;
        if (lexless(d, j, best, bidx)) { best = d; bidx = j; }
    }
    for (int off = 1; off < 64; off <<= 1) {
        float ov = __shfl_xor(best, off);
        int   oi = __shfl_xor(bidx, off);
        if (lexless(ov, oi, best, bidx)) { best = ov; bidx = oi; }
    }
    if (lane == 0) sta_ind[i] = bidx;
}

// ---------------------------------------------------------------------------
// Kernel 2 (v4): histogram select with NO distance storage.
// Pass 1: compute d, build 2048-bin histogram of bits>>20 (monotonic key).
// Wave 0: prefix-scan bins -> boundary bin B (cumulative count >= 15).
// Pass 2: recompute d (bit-identical), append (g,d) with key <= B (~17).
// Wave 0: lex-sort survivors, write 15 ascending (dq, g), mark used.
// Fallback (survivors > CAP, never expected): 15 rounds of block argmin
// with recompute + exclusion list. Correct for any data.
// ---------------------------------------------------------------------------
__global__ __launch_bounds__(256, 8) void topk_kernel(const float* __restrict__ src,
                                                      const float* __restrict__ x_grid,
                                                      int* __restrict__ idx_out,
                                                      int* __restrict__ used) {
#pragma clang fp contract(off)
    const int s    = blockIdx.x;
    const int tid  = threadIdx.x;
    const int lane = tid & 63;
    const int wv   = tid >> 6;

    __shared__ unsigned int s_hist[NBIN];   // 8 KB
    __shared__ int          s_cand[CAP];    // 2 KB
    __shared__ float        s_cd[CAP];      // 2 KB
    __shared__ int          s_cnt;
    __shared__ int          s_binB;
    __shared__ int          s_nle;
    __shared__ float        s_mv[4];
    __shared__ int          s_mi[4];
    __shared__ int          s_ch[KK];

    for (int b = tid; b < NBIN; b += 256) s_hist[b] = 0u;
    if (tid == 0) s_cnt = 0;
    __syncthreads();

    const float sx = tr1k(src[s * 3 + 0]);
    const float sy = tr1k(src[s * 3 + 1]);
    const float sz = tr1k(src[s * 3 + 2]);

    // pass 1: histogram only
    for (int g = tid; g < G_N; g += 256) {
        float dx = sx - tr1k(x_grid[g * 3 + 0]);
        float dy = sy - tr1k(x_grid[g * 3 + 1]);
        float dz = sz - tr1k(x_grid[g * 3 + 2]);
        float d  = (dx * dx + dy * dy) + dz * dz;
        atomicAdd(&s_hist[__float_as_uint(d) >> 20], 1u);
    }
    __syncthreads();

    // wave 0: find boundary bin
    if (wv == 0) {
        const int chunk = NBIN / 64;           // 32 bins per lane
        const int base  = lane * chunk;
        unsigned int cs = 0;
        for (int b = 0; b < chunk; ++b) cs += s_hist[base + b];
        unsigned int pfx = cs;
        for (int off = 1; off < 64; off <<= 1) {
            unsigned int o = __shfl_up(pfx, off);
            if (lane >= off) pfx += o;
        }
        unsigned long long m = __ballot(pfx >= (unsigned)KK);
        int fl = __ffsll((unsigned long long)m) - 1;
        if (lane == fl) {
            unsigned int acc = pfx - cs;       // cumulative before this chunk (< KK)
            int b = base;
            for (;;) {
                acc += s_hist[b];
                if (acc >= (unsigned)KK) break;
                ++b;
            }
            s_binB = b;
            s_nle  = (int)acc;                 // count of keys <= B
        }
    }
    __syncthreads();

    const int binB = s_binB;
    const int nle  = s_nle;

    if (nle <= CAP) {
        // pass 2: recompute, append survivors
        for (int g = tid; g < G_N; g += 256) {
            float dx = sx - tr1k(x_grid[g * 3 + 0]);
            float dy = sy - tr1k(x_grid[g * 3 + 1]);
            float dz = sz - tr1k(x_grid[g * 3 + 2]);
            float d  = (dx * dx + dy * dy) + dz * dz;
            if ((int)(__float_as_uint(d) >> 20) <= binB) {
                int p = atomicAdd(&s_cnt, 1);
                s_cand[p] = g;
                s_cd[p]   = d;
            }
        }
        __syncthreads();
        if (wv == 0) {
            const int n = s_cnt;
            float vals[KK];
            int   ids[KK];
#pragma unroll
            for (int j = 0; j < KK; ++j) { vals[j] = INFINITY; ids[j] = 0x7fffffff; }
            for (int c = lane; c < n; c += 64) {
                int   g = s_cand[c];
                float d = s_cd[c];
                if (lexless(d, g, vals[KK - 1], ids[KK - 1])) {
                    float cv = d; int ci = g;
#pragma unroll
                    for (int j = 0; j < KK; ++j) {
                        bool sw = lexless(cv, ci, vals[j], ids[j]);
                        float tv = sw ? vals[j] : cv;
                        int   ti = sw ? ids[j]  : ci;
                        vals[j]  = sw ? cv : vals[j];
                        ids[j]   = sw ? ci : ids[j];
                        cv = tv; ci = ti;
                    }
                }
            }
            for (int r = 0; r < KK; ++r) {
                float v  = vals[0];
                int   id = ids[0];
                int   who = lane;
                for (int off = 1; off < 64; off <<= 1) {
                    float ov = __shfl_xor(v, off);
                    int   oi = __shfl_xor(id, off);
                    int   ow = __shfl_xor(who, off);
                    if (lexless(ov, oi, v, id)) { v = ov; id = oi; who = ow; }
                }
                if (lane == 0) {
                    idx_out[s * KK + r] = id;
                    if (used) used[id] = 1;    // benign race; all writers store 1
                }
                if (who == lane) {
#pragma unroll
                    for (int j = 0; j < KK - 1; ++j) { vals[j] = vals[j + 1]; ids[j] = ids[j + 1]; }
                    vals[KK - 1] = INFINITY;
                    ids[KK - 1]  = 0x7fffffff;
                }
            }
        }
    } else {
        // slow exact fallback: 15 rounds of block argmin with recompute +
        // exclusion list (deterministic; not expected to trigger)
        for (int r = 0; r < KK; ++r) {
            float v  = INFINITY;
            int   id = 0x7fffffff;
            for (int g = tid; g < G_N; g += 256) {
                bool skip = false;
                for (int j = 0; j < r; ++j) skip = skip || (s_ch[j] == g);
                if (skip) continue;
                float dx = sx - tr1k(x_grid[g * 3 + 0]);
                float dy = sy - tr1k(x_grid[g * 3 + 1]);
                float dz = sz - tr1k(x_grid[g * 3 + 2]);
                float d  = (dx * dx + dy * dy) + dz * dz;
                if (lexless(d, g, v, id)) { v = d; id = g; }
            }
            for (int off = 1; off < 64; off <<= 1) {
                float ov = __shfl_xor(v, off);
                int   oi = __shfl_xor(id, off);
                if (lexless(ov, oi, v, id)) { v = ov; id = oi; }
            }
            if (lane == 0) { s_mv[wv] = v; s_mi[wv] = id; }
            __syncthreads();
            if (tid == 0) {
                float bv = s_mv[0]; int bi = s_mi[0];
                for (int w = 1; w < 4; ++w)
                    if (lexless(s_mv[w], s_mi[w], bv, bi)) { bv = s_mv[w]; bi = s_mi[w]; }
                s_ch[r] = bi;
                idx_out[s * KK + r] = bi;
                if (used) used[bi] = 1;
            }
            __syncthreads();
        }
    }
}

// ---------------------------------------------------------------------------
// Kernel 3: pack (fp16 output). One block per used g. Stages the 12 KB ker
// row + 8 KB coef row into LDS (float4 coalesced), gathers the 400 station
// columns, folds fast-softplus -> reciprocal and the phase select, writes
// 8 B/station: {h(1/spk0), h(1/spk1), h(1/spk2), h(c_sel)} at [g][i].
// ---------------------------------------------------------------------------
__global__ __launch_bounds__(256) void pack_kernel(
    const float* __restrict__ coefs, const float* __restrict__ coefs_ker,
    const int* __restrict__ sta_ind, const int* __restrict__ phase,
    const int* __restrict__ used,
    uint2* __restrict__ pk)
{
    const int g = blockIdx.x;
    if (!used[g]) return;            // wave-uniform early exit
    const int tid = threadIdx.x;

    __shared__ float s_ker[L_N * 3];
    __shared__ float s_c[L_N * 2];

    const float4* kr4 = (const float4*)(coefs_ker + (size_t)g * (L_N * 3)); // 750 vec4
    const float4* cr4 = (const float4*)(coefs     + (size_t)g * (L_N * 2)); // 500 vec4
    float4* sk4 = (float4*)s_ker;
    float4* sc4 = (float4*)s_c;
#pragma unroll
    for (int j = 0; j < 3; ++j) {
        int p = tid + j * 256;
        if (p < (L_N * 3) / 4) sk4[p] = kr4[p];
    }
#pragma unroll
    for (int j = 0; j < 2; ++j) {
        int p = tid + j * 256;
        if (p < (L_N * 2) / 4) sc4[p] = cr4[p];
    }
    // prefetch station gather indices (coalesced) before the barrier
    const int i1 = tid + 256;
    const int st0 = sta_ind[tid];                       // tid < 256 <= NSTA
    const int ph0 = phase[tid];
    const int st1 = (i1 < NSTA) ? sta_ind[i1] : 0;
    const int ph1 = (i1 < NSTA) ? phase[i1] : 0;
    __syncthreads();

    {
        float rk0 = 1.0f / softplus_fast(s_ker[st0 * 3 + 0]);
        float rk1 = 1.0f / softplus_fast(s_ker[st0 * 3 + 1]);
        float rk2 = 1.0f / softplus_fast(s_ker[st0 * 3 + 2]);
        float c   = (ph0 == 0) ? s_c[st0 * 2 + 0] : s_c[st0 * 2 + 1];
        __half2 a = __floats2half2_rn(rk0, rk1);
        __half2 b = __floats2half2_rn(rk2, c);
        uint2 u;
        u.x = *reinterpret_cast<unsigned int*>(&a);
        u.y = *reinterpret_cast<unsigned int*>(&b);
        pk[(size_t)g * NSTA + tid] = u;
    }
    if (i1 < NSTA) {
        float rk0 = 1.0f / softplus_fast(s_ker[st1 * 3 + 0]);
        float rk1 = 1.0f / softplus_fast(s_ker[st1 * 3 + 1]);
        float rk2 = 1.0f / softplus_fast(s_ker[st1 * 3 + 2]);
        float c   = (ph1 == 0) ? s_c[st1 * 2 + 0] : s_c[st1 * 2 + 1];
        __half2 a = __floats2half2_rn(rk0, rk1);
        __half2 b = __floats2half2_rn(rk2, c);
        uint2 u;
        u.x = *reinterpret_cast<unsigned int*>(&a);
        u.y = *reinterpret_cast<unsigned int*>(&b);
        pk[(size_t)g * NSTA + i1] = u;
    }
}

// ---------------------------------------------------------------------------
// Kernel 4: main fused computation, fast path. Block per src, coalesced
// 8 B reads of the fp16-packed table.
// ---------------------------------------------------------------------------
__global__ __launch_bounds__(256) void magnitude_fast_kernel(
    const float* __restrict__ sta, const float* __restrict__ src,
    const float* __restrict__ mag, const int* __restrict__ phase,
    const float* __restrict__ x_grid,
    const float* __restrict__ mag_coef, const float* __restrict__ epi_coef,
    const float* __restrict__ dep_coef,
    const uint2* __restrict__ pk, const int* __restrict__ idx,
    float* __restrict__ out)
{
    const int s   = blockIdx.x;
    const int tid = threadIdx.x;

    __shared__ float s_diff[KK][3];
    __shared__ int   s_g[KK];

    if (tid < KK) {
        int g = idx[s * KK + tid];
        s_g[tid] = g;
        s_diff[tid][0] = tr1k(x_grid[g * 3 + 0]) - tr1k(src[s * 3 + 0]);
        s_diff[tid][1] = tr1k(x_grid[g * 3 + 1]) - tr1k(src[s * 3 + 1]);
        s_diff[tid][2] = tr1k(x_grid[g * 3 + 2]) - tr1k(src[s * 3 + 2]);
    }
    __syncthreads();

    const float mag_s = mag[s];
    const float srcx = src[s * 3 + 0];
    const float srcy = src[s * 3 + 1];
    const float srcz = src[s * 3 + 2];
    const float sp_mc0 = softplus(mag_coef[0]), sp_mc1 = softplus(mag_coef[1]);
    const float sp_ec0 = softplus(epi_coef[0]), sp_ec1 = softplus(epi_coef[1]);
    const float dc0 = dep_coef[0], dc1 = dep_coef[1];

    for (int i = tid; i < NSTA; i += 256) {
        float wsum = 0.0f, a = 0.0f;
#pragma unroll
        for (int k = 0; k < KK; ++k) {
            uint2 u = pk[(size_t)s_g[k] * NSTA + i];
            __half2 h01 = *reinterpret_cast<const __half2*>(&u.x);
            __half2 h23 = *reinterpret_cast<const __half2*>(&u.y);
            float2 f01 = __half22float2(h01);
            float2 f23 = __half22float2(h23);
            float t0 = s_diff[k][0] * f01.x;
            float t1 = s_diff[k][1] * f01.y;
            float t2 = s_diff[k][2] * f23.x;
            float e  = __expf(-0.5f * ((t0 * t0 + t1 * t1) + t2 * t2));
            wsum += e;
            a    += e * f23.y;
        }
        if (wsum == 0.0f) wsum = 1.0f;

        const int ph = phase[i];
        float bias = a / wsum;

        float dx = srcx * 1000.0f - sta[i * 3 + 0] * 1000.0f;
        float dy = srcy * 1000.0f - sta[i * 3 + 1] * 1000.0f;
        float lz = __log10f(__fsqrt_rn(dx * dx + dy * dy) + 1.0f);
        float ld = __log10f(fabsf(srcz - sta[i * 3 + 2]) + 1.0f);

        float mc = (ph == 0) ? sp_mc0 : sp_mc1;
        float ec = (ph == 0) ? sp_ec0 : sp_ec1;
        float dc = (ph == 0) ? dc0 : dc1;

        out[(size_t)s * NSTA + i] = mag_s * mc - ec * lz + dc * ld + bias;
    }
}

// ---------------------------------------------------------------------------
// Fallback main kernel (direct gather) if ws_size can't hold the packed table.
// ---------------------------------------------------------------------------
__global__ __launch_bounds__(256) void magnitude_kernel(
    const float* __restrict__ sta, const float* __restrict__ src,
    const float* __restrict__ mag, const int* __restrict__ phase,
    const float* __restrict__ x_grid,
    const float* __restrict__ mag_coef, const float* __restrict__ epi_coef,
    const float* __restrict__ dep_coef,
    const float* __restrict__ coefs, const float* __restrict__ coefs_ker,
    const int* __restrict__ sta_ind, const int* __restrict__ idx,
    float* __restrict__ out)
{
    const int s   = blockIdx.x;
    const int tid = threadIdx.x;

    __shared__ float s_diff[KK][3];
    __shared__ int   s_g[KK];
    __shared__ int   s_sta[NSTA];

    if (tid < KK) {
        int g = idx[s * KK + tid];
        s_g[tid] = g;
        s_diff[tid][0] = tr1k(x_grid[g * 3 + 0]) - tr1k(src[s * 3 + 0]);
        s_diff[tid][1] = tr1k(x_grid[g * 3 + 1]) - tr1k(src[s * 3 + 1]);
        s_diff[tid][2] = tr1k(x_grid[g * 3 + 2]) - tr1k(src[s * 3 + 2]);
    }
    for (int i = tid; i < NSTA; i += 256) s_sta[i] = sta_ind[i];
    __syncthreads();

    const float mag_s = mag[s];
    const float srcx = src[s * 3 + 0];
    const float srcy = src[s * 3 + 1];
    const float srcz = src[s * 3 + 2];
    const float sp_mc0 = softplus(mag_coef[0]), sp_mc1 = softplus(mag_coef[1]);
    const float sp_ec0 = softplus(epi_coef[0]), sp_ec1 = softplus(epi_coef[1]);
    const float dc0 = dep_coef[0], dc1 = dep_coef[1];

    for (int i = tid; i < NSTA; i += 256) {
        const int st = s_sta[i];
        float wsum = 0.0f, a0 = 0.0f, a1 = 0.0f;
#pragma unroll
        for (int k = 0; k < KK; ++k) {
            const int g = s_g[k];
            const float* kp = coefs_ker + ((size_t)g * L_N + st) * 3;
            float k0 = softplus(kp[0]);
            float k1 = softplus(kp[1]);
            float k2 = softplus(kp[2]);
            float t0 = s_diff[k][0] / k0;
            float t1 = s_diff[k][1] / k1;
            float t2 = s_diff[k][2] / k2;
            float e  = expf(-0.5f * ((t0 * t0 + t1 * t1) + t2 * t2));
            const float* cp = coefs + ((size_t)g * L_N + st) * 2;
            wsum += e;
            a0 += e * cp[0];
            a1 += e * cp[1];
        }
        if (wsum == 0.0f) wsum = 1.0f;

        const int ph = phase[i];
        float bias = ((ph == 0) ? a0 : a1) / wsum;

        float dx = srcx * 1000.0f - sta[i * 3 + 0] * 1000.0f;
        float dy = srcy * 1000.0f - sta[i * 3 + 1] * 1000.0f;
        float lz = log10f(sqrtf(dx * dx + dy * dy) + 1.0f);
        float ld = log10f(fabsf(srcz - sta[i * 3 + 2]) + 1.0f);

        float mc = (ph == 0) ? sp_mc0 : sp_mc1;
        float ec = (ph == 0) ? sp_ec0 : sp_ec1;
        float dc = (ph == 0) ? dc0 : dc1;

        out[(size_t)s * NSTA + i] = mag_s * mc - ec * lz + dc * ld + bias;
    }
}

extern "C" void kernel_launch(void* const* d_in, const int* in_sizes, int n_in,
                              void* d_out, int out_size, void* d_ws, size_t ws_size,
                              hipStream_t stream) {
    const float* sta       = (const float*)d_in[0];
    const float* src       = (const float*)d_in[1];
    const float* mag       = (const float*)d_in[2];
    const int*   phase     = (const int*)d_in[3];
    const float* x_grid    = (const float*)d_in[4];
    const float* locs_ref  = (const float*)d_in[5];
    const float* mag_coef  = (const float*)d_in[6];
    const float* epi_coef  = (const float*)d_in[7];
    const float* dep_coef  = (const float*)d_in[8];
    const float* coefs     = (const float*)d_in[9];
    const float* coefs_ker = (const float*)d_in[10];
    float* out = (float*)d_out;

    const size_t pk_bytes = (size_t)G_N * NSTA * sizeof(uint2);   // 32 MB
    const size_t need_fast = pk_bytes
                           + (size_t)NSRC * KK * sizeof(int)
                           + (size_t)NSTA * sizeof(int)
                           + (size_t)G_N * sizeof(int);

    if (ws_size >= need_fast) {
        uint2* ws_pk   = (uint2*)d_ws;
        int* ws_idx    = (int*)((char*)d_ws + pk_bytes);
        int* ws_sta    = ws_idx + (size_t)NSRC * KK;
        int* ws_used   = ws_sta + NSTA;

        hipLaunchKernelGGL(sta_ind_kernel, dim3(NSTA), dim3(64), 0, stream,
                           sta, locs_ref, ws_sta, ws_used);
        hipLaunchKernelGGL(topk_kernel, dim3(NSRC), dim3(256), 0, stream,
                           src, x_grid, ws_idx, ws_used);
        hipLaunchKernelGGL(pack_kernel, dim3(G_N), dim3(256), 0, stream,
                           coefs, coefs_ker, ws_sta, phase, ws_used, ws_pk);
        hipLaunchKernelGGL(magnitude_fast_kernel, dim3(NSRC), dim3(256), 0, stream,
                           sta, src, mag, phase, x_grid,
                           mag_coef, epi_coef, dep_coef,
                           ws_pk, ws_idx, out);
    } else {
        int* ws_sta = (int*)d_ws;
        int* ws_idx = ws_sta + NSTA;

        hipLaunchKernelGGL(sta_ind_kernel, dim3(NSTA), dim3(64), 0, stream,
                           sta, locs_ref, ws_sta, (int*)nullptr);
        hipLaunchKernelGGL(topk_kernel, dim3(NSRC), dim3(256), 0, stream,
                           src, x_grid, ws_idx, (int*)nullptr);
        hipLaunchKernelGGL(magnitude_kernel, dim3(NSRC), dim3(256), 0, stream,
                           sta, src, mag, phase, x_grid,
                           mag_coef, epi_coef, dep_coef,
                           coefs, coefs_ker, ws_sta, ws_idx, out);
    }
}

// Round 8
// 136.598 us; speedup vs baseline: 1.2991x; 1.0134x over previous
//
#include <hip/hip_runtime.h>
#include <hip/hip_fp16.h>
#include <cstddef>

#define G_N   10000
#define L_N   1000
#define NSTA  400
#define NSRC  2000
#define KK    15
#define CAP   2048
#define LDSB  20480
#define CTLO  (1024 + 8 * CAP)    // 17408: control block offset in s_raw

__device__ __forceinline__ float tr1k(float x) {
    // matches reference: _ftrns(x)/1000.0 = (x*1000.0f)/1000.0f, exact f32 div
    return (x * 1000.0f) / 1000.0f;
}

__device__ __forceinline__ float softplus(float x) {
    return fmaxf(x, 0.0f) + log1pf(expf(-fabsf(x)));
}

__device__ __forceinline__ float softplus_fast(float x) {
    return fmaxf(x, 0.0f) + __logf(1.0f + __expf(-fabsf(x)));
}

__device__ __forceinline__ bool lexless(float v1, int i1, float v2, int i2) {
    return (v1 < v2) || (v1 == v2 && i1 < i2);
}

// ---------------------------------------------------------------------------
// Kernel 1: sta_ind argmin (one wave per station) + tr1k precompute tables.
// tg[3*G_N] = tr1k(x_grid), ts[3*NSRC] = tr1k(src): hoists all divisions
// out of topk's hot loop.
// ---------------------------------------------------------------------------
__global__ void sta_prep_kernel(const float* __restrict__ sta,
                                const float* __restrict__ locs_ref,
                                const float* __restrict__ x_grid,
                                const float* __restrict__ src,
                                int* __restrict__ sta_ind,
                                float* __restrict__ tg,
                                float* __restrict__ ts) {
#pragma clang fp contract(off)
    const int i    = blockIdx.x;
    const int lane = threadIdx.x;

    // prep: 30000 + 6000 elements over 400*64 = 25600 threads (2 iters max)
    const int z = i * 64 + lane;
    for (int p = z; p < 3 * (G_N + NSRC); p += 400 * 64) {
        if (p < 3 * G_N) tg[p] = tr1k(x_grid[p]);
        else             ts[p - 3 * G_N] = tr1k(src[p - 3 * G_N]);
    }

    const float sx = tr1k(sta[i * 3 + 0]);
    const float sy = tr1k(sta[i * 3 + 1]);
    const float sz = tr1k(sta[i * 3 + 2]);
    float best = INFINITY;
    int   bidx = 0x7fffffff;
    for (int j = lane; j < L_N; j += 64) {
        float dx = sx - tr1k(locs_ref[j * 3 + 0]);
        float dy = sy - tr1k(locs_ref[j * 3 + 1]);
        float dz = sz - tr1k(locs_ref[j * 3 + 2]);
        float d  = (dx * dx + dy * dy) + dz * dz;
        if (lexless(d, j, best, bidx)) { best = d; bidx = j; }
    }
    for (int off = 1; off < 64; off <<= 1) {
        float ov = __shfl_xor(best, off);
        int   oi = __shfl_xor(bidx, off);
        if (lexless(ov, oi, best, bidx)) { best = ov; bidx = oi; }
    }
    if (lane == 0) sta_ind[i] = bidx;
}

// ---------------------------------------------------------------------------
// topk block body (v5): exact threshold select, no histogram, no divisions.
// Pass 1: per-thread min over its ~40 candidates -> s_min[256].
// Wave 0: T = 15th smallest of the 256 minima (register 4-per-lane,
//         15 rounds of lex wave-argmin-extract). Guarantees:
//         count(d<=T) >= 15 and top-15 subset of {d<=T}.
// Pass 2: recompute d (bit-identical), append survivors (d<=T), ~20-40.
// Wave 0: exact lex sort of survivors -> 15 ascending (dq, g).
// Fallback n>CAP (degenerate ties only): 15 block argmin rounds w/ exclusion.
// ---------------------------------------------------------------------------
__device__ __forceinline__ void topk_block(int s,
                                           const float* __restrict__ tg,
                                           const float* __restrict__ ts,
                                           int* __restrict__ idx_out,
                                           char* s_raw, int tid) {
#pragma clang fp contract(off)
    const int lane = tid & 63;
    const int wv   = tid >> 6;

    float* s_min  = (float*)s_raw;                 // 1 KB
    int*   s_cand = (int*)(s_raw + 1024);          // 8 KB
    float* s_cd   = (float*)(s_raw + 1024 + 4 * CAP); // 8 KB
    float* s_T    = (float*)(s_raw + CTLO);
    int*   s_cnt  = (int*)(s_raw + CTLO + 4);
    float* s_mv   = (float*)(s_raw + CTLO + 8);    // 4
    int*   s_mi   = (int*)(s_raw + CTLO + 24);     // 4
    int*   s_ch   = (int*)(s_raw + CTLO + 40);     // 15

    if (tid == 0) *s_cnt = 0;

    const float sx = ts[s * 3 + 0];
    const float sy = ts[s * 3 + 1];
    const float sz = ts[s * 3 + 2];

    // pass 1: per-thread min value
    float mymin = INFINITY;
    for (int g = tid; g < G_N; g += 256) {
        float dx = sx - tg[g * 3 + 0];
        float dy = sy - tg[g * 3 + 1];
        float dz = sz - tg[g * 3 + 2];
        float d  = (dx * dx + dy * dy) + dz * dz;
        mymin = fminf(mymin, d);
    }
    s_min[tid] = mymin;
    __syncthreads();

    // wave 0: T = 15th smallest of 256 minima
    if (wv == 0) {
        float m0 = s_min[lane];
        float m1 = s_min[lane + 64];
        float m2 = s_min[lane + 128];
        float m3 = s_min[lane + 192];
        float T = INFINITY;
        for (int r = 0; r < KK; ++r) {
            float lv = m0; int ls = 0;
            if (m1 < lv) { lv = m1; ls = 1; }
            if (m2 < lv) { lv = m2; ls = 2; }
            if (m3 < lv) { lv = m3; ls = 3; }
            float v = lv; int wl = lane;
            for (int off = 1; off < 64; off <<= 1) {
                float ov = __shfl_xor(v, off);
                int   ol = __shfl_xor(wl, off);
                if (ov < v || (ov == v && ol < wl)) { v = ov; wl = ol; }
            }
            T = v;
            if (wl == lane) {
                if (ls == 0) m0 = INFINITY;
                else if (ls == 1) m1 = INFINITY;
                else if (ls == 2) m2 = INFINITY;
                else m3 = INFINITY;
            }
        }
        if (lane == 0) *s_T = T;
    }
    __syncthreads();
    const float T = *s_T;

    // pass 2: recompute, append survivors
    for (int g = tid; g < G_N; g += 256) {
        float dx = sx - tg[g * 3 + 0];
        float dy = sy - tg[g * 3 + 1];
        float dz = sz - tg[g * 3 + 2];
        float d  = (dx * dx + dy * dy) + dz * dz;
        if (d <= T) {
            int p = atomicAdd(s_cnt, 1);
            if (p < CAP) { s_cand[p] = g; s_cd[p] = d; }
        }
    }
    __syncthreads();
    const int n = *s_cnt;

    if (n <= CAP) {
        if (wv == 0) {
            float vals[KK];
            int   ids[KK];
#pragma unroll
            for (int j = 0; j < KK; ++j) { vals[j] = INFINITY; ids[j] = 0x7fffffff; }
            for (int c = lane; c < n; c += 64) {
                int   g = s_cand[c];
                float d = s_cd[c];
                if (lexless(d, g, vals[KK - 1], ids[KK - 1])) {
                    float cv = d; int ci = g;
#pragma unroll
                    for (int j = 0; j < KK; ++j) {
                        bool sw = lexless(cv, ci, vals[j], ids[j]);
                        float tv = sw ? vals[j] : cv;
                        int   ti = sw ? ids[j]  : ci;
                        vals[j]  = sw ? cv : vals[j];
                        ids[j]   = sw ? ci : ids[j];
                        cv = tv; ci = ti;
                    }
                }
            }
            for (int r = 0; r < KK; ++r) {
                float v  = vals[0];
                int   id = ids[0];
                int   who = lane;
                for (int off = 1; off < 64; off <<= 1) {
                    float ov = __shfl_xor(v, off);
                    int   oi = __shfl_xor(id, off);
                    int   ow = __shfl_xor(who, off);
                    if (lexless(ov, oi, v, id)) { v = ov; id = oi; who = ow; }
                }
                if (lane == 0) idx_out[s * KK + r] = id;
                if (who == lane) {
#pragma unroll
                    for (int j = 0; j < KK - 1; ++j) { vals[j] = vals[j + 1]; ids[j] = ids[j + 1]; }
                    vals[KK - 1] = INFINITY;
                    ids[KK - 1]  = 0x7fffffff;
                }
            }
        }
    } else {
        // degenerate-ties fallback: exact 15 rounds of block argmin
        for (int r = 0; r < KK; ++r) {
            float v  = INFINITY;
            int   id = 0x7fffffff;
            for (int g = tid; g < G_N; g += 256) {
                bool skip = false;
                for (int j = 0; j < r; ++j) skip = skip || (s_ch[j] == g);
                if (skip) continue;
                float dx = sx - tg[g * 3 + 0];
                float dy = sy - tg[g * 3 + 1];
                float dz = sz - tg[g * 3 + 2];
                float d  = (dx * dx + dy * dy) + dz * dz;
                if (lexless(d, g, v, id)) { v = d; id = g; }
            }
            for (int off = 1; off < 64; off <<= 1) {
                float ov = __shfl_xor(v, off);
                int   oi = __shfl_xor(id, off);
                if (lexless(ov, oi, v, id)) { v = ov; id = oi; }
            }
            if (lane == 0) { s_mv[wv] = v; s_mi[wv] = id; }
            __syncthreads();
            if (tid == 0) {
                float bv = s_mv[0]; int bi = s_mi[0];
                for (int w = 1; w < 4; ++w)
                    if (lexless(s_mv[w], s_mi[w], bv, bi)) { bv = s_mv[w]; bi = s_mi[w]; }
                s_ch[r] = bi;
                idx_out[s * KK + r] = bi;
            }
            __syncthreads();
        }
    }
}

// ---------------------------------------------------------------------------
// pack block body: stage ker/coef rows in LDS (float4 coalesced), gather 400
// station columns, fold fast-softplus reciprocal + phase select, write fp16x4.
// ---------------------------------------------------------------------------
__device__ __forceinline__ void pack_block(int g,
                                           const float* __restrict__ coefs,
                                           const float* __restrict__ coefs_ker,
                                           const int* __restrict__ sta_ind,
                                           const int* __restrict__ phase,
                                           uint2* __restrict__ pk,
                                           char* s_raw, int tid) {
    float* s_ker = (float*)s_raw;             // 12 KB
    float* s_c   = (float*)(s_raw + 12288);   // 8 KB

    const float4* kr4 = (const float4*)(coefs_ker + (size_t)g * (L_N * 3));
    const float4* cr4 = (const float4*)(coefs     + (size_t)g * (L_N * 2));
    float4* sk4 = (float4*)s_ker;
    float4* sc4 = (float4*)s_c;
#pragma unroll
    for (int j = 0; j < 3; ++j) {
        int p = tid + j * 256;
        if (p < (L_N * 3) / 4) sk4[p] = kr4[p];
    }
#pragma unroll
    for (int j = 0; j < 2; ++j) {
        int p = tid + j * 256;
        if (p < (L_N * 2) / 4) sc4[p] = cr4[p];
    }
    const int i1  = tid + 256;
    const int st0 = sta_ind[tid];
    const int ph0 = phase[tid];
    const int st1 = (i1 < NSTA) ? sta_ind[i1] : 0;
    const int ph1 = (i1 < NSTA) ? phase[i1] : 0;
    __syncthreads();

    {
        float rk0 = 1.0f / softplus_fast(s_ker[st0 * 3 + 0]);
        float rk1 = 1.0f / softplus_fast(s_ker[st0 * 3 + 1]);
        float rk2 = 1.0f / softplus_fast(s_ker[st0 * 3 + 2]);
        float c   = (ph0 == 0) ? s_c[st0 * 2 + 0] : s_c[st0 * 2 + 1];
        __half2 a = __floats2half2_rn(rk0, rk1);
        __half2 b = __floats2half2_rn(rk2, c);
        uint2 u;
        u.x = *reinterpret_cast<unsigned int*>(&a);
        u.y = *reinterpret_cast<unsigned int*>(&b);
        pk[(size_t)g * NSTA + tid] = u;
    }
    if (i1 < NSTA) {
        float rk0 = 1.0f / softplus_fast(s_ker[st1 * 3 + 0]);
        float rk1 = 1.0f / softplus_fast(s_ker[st1 * 3 + 1]);
        float rk2 = 1.0f / softplus_fast(s_ker[st1 * 3 + 2]);
        float c   = (ph1 == 0) ? s_c[st1 * 2 + 0] : s_c[st1 * 2 + 1];
        __half2 a = __floats2half2_rn(rk0, rk1);
        __half2 b = __floats2half2_rn(rk2, c);
        uint2 u;
        u.x = *reinterpret_cast<unsigned int*>(&a);
        u.y = *reinterpret_cast<unsigned int*>(&b);
        pk[(size_t)g * NSTA + i1] = u;
    }
}

// ---------------------------------------------------------------------------
// Fused kernel: 12000 blocks, 5:1 interleave pack:topk so the BW-bound pack
// waves and VALU-bound topk waves co-schedule on every CU.
// ---------------------------------------------------------------------------
__global__ __launch_bounds__(256, 8) void fused_kernel(
    const float* __restrict__ coefs, const float* __restrict__ coefs_ker,
    const int* __restrict__ sta_ind, const int* __restrict__ phase,
    uint2* __restrict__ pk,
    const float* __restrict__ tg, const float* __restrict__ ts,
    int* __restrict__ idx_out)
{
    __shared__ __align__(16) char s_raw[LDSB];
    const int bid = blockIdx.x;
    const int t = bid / 6, r = bid % 6;
    if (r == 5) {
        topk_block(t, tg, ts, idx_out, s_raw, threadIdx.x);
    } else {
        pack_block(t * 5 + r, coefs, coefs_ker, sta_ind, phase, pk, s_raw, threadIdx.x);
    }
}

// standalone topk (fallback path without pk workspace)
__global__ __launch_bounds__(256, 8) void topk_only_kernel(
    const float* __restrict__ tg, const float* __restrict__ ts,
    int* __restrict__ idx_out)
{
    __shared__ __align__(16) char s_raw[LDSB];
    topk_block(blockIdx.x, tg, ts, idx_out, s_raw, threadIdx.x);
}

// ---------------------------------------------------------------------------
// Kernel 4: main fused computation, fast path (fp16 packed table).
// ---------------------------------------------------------------------------
__global__ __launch_bounds__(256) void magnitude_fast_kernel(
    const float* __restrict__ sta, const float* __restrict__ src,
    const float* __restrict__ mag, const int* __restrict__ phase,
    const float* __restrict__ x_grid,
    const float* __restrict__ mag_coef, const float* __restrict__ epi_coef,
    const float* __restrict__ dep_coef,
    const uint2* __restrict__ pk, const int* __restrict__ idx,
    float* __restrict__ out)
{
    const int s   = blockIdx.x;
    const int tid = threadIdx.x;

    __shared__ float s_diff[KK][3];
    __shared__ int   s_g[KK];

    if (tid < KK) {
        int g = idx[s * KK + tid];
        s_g[tid] = g;
        s_diff[tid][0] = tr1k(x_grid[g * 3 + 0]) - tr1k(src[s * 3 + 0]);
        s_diff[tid][1] = tr1k(x_grid[g * 3 + 1]) - tr1k(src[s * 3 + 1]);
        s_diff[tid][2] = tr1k(x_grid[g * 3 + 2]) - tr1k(src[s * 3 + 2]);
    }
    __syncthreads();

    const float mag_s = mag[s];
    const float srcx = src[s * 3 + 0];
    const float srcy = src[s * 3 + 1];
    const float srcz = src[s * 3 + 2];
    const float sp_mc0 = softplus(mag_coef[0]), sp_mc1 = softplus(mag_coef[1]);
    const float sp_ec0 = softplus(epi_coef[0]), sp_ec1 = softplus(epi_coef[1]);
    const float dc0 = dep_coef[0], dc1 = dep_coef[1];

    for (int i = tid; i < NSTA; i += 256) {
        float wsum = 0.0f, a = 0.0f;
#pragma unroll
        for (int k = 0; k < KK; ++k) {
            uint2 u = pk[(size_t)s_g[k] * NSTA + i];
            __half2 h01 = *reinterpret_cast<const __half2*>(&u.x);
            __half2 h23 = *reinterpret_cast<const __half2*>(&u.y);
            float2 f01 = __half22float2(h01);
            float2 f23 = __half22float2(h23);
            float t0 = s_diff[k][0] * f01.x;
            float t1 = s_diff[k][1] * f01.y;
            float t2 = s_diff[k][2] * f23.x;
            float e  = __expf(-0.5f * ((t0 * t0 + t1 * t1) + t2 * t2));
            wsum += e;
            a    += e * f23.y;
        }
        if (wsum == 0.0f) wsum = 1.0f;

        const int ph = phase[i];
        float bias = a / wsum;

        float dx = srcx * 1000.0f - sta[i * 3 + 0] * 1000.0f;
        float dy = srcy * 1000.0f - sta[i * 3 + 1] * 1000.0f;
        float lz = __log10f(__fsqrt_rn(dx * dx + dy * dy) + 1.0f);
        float ld = __log10f(fabsf(srcz - sta[i * 3 + 2]) + 1.0f);

        float mc = (ph == 0) ? sp_mc0 : sp_mc1;
        float ec = (ph == 0) ? sp_ec0 : sp_ec1;
        float dc = (ph == 0) ? dc0 : dc1;

        out[(size_t)s * NSTA + i] = mag_s * mc - ec * lz + dc * ld + bias;
    }
}

// ---------------------------------------------------------------------------
// Fallback main kernel (direct gather) if ws can't hold the packed table.
// ---------------------------------------------------------------------------
__global__ __launch_bounds__(256) void magnitude_kernel(
    const float* __restrict__ sta, const float* __restrict__ src,
    const float* __restrict__ mag, const int* __restrict__ phase,
    const float* __restrict__ x_grid,
    const float* __restrict__ mag_coef, const float* __restrict__ epi_coef,
    const float* __restrict__ dep_coef,
    const float* __restrict__ coefs, const float* __restrict__ coefs_ker,
    const int* __restrict__ sta_ind, const int* __restrict__ idx,
    float* __restrict__ out)
{
    const int s   = blockIdx.x;
    const int tid = threadIdx.x;

    __shared__ float s_diff[KK][3];
    __shared__ int   s_g[KK];
    __shared__ int   s_sta[NSTA];

    if (tid < KK) {
        int g = idx[s * KK + tid];
        s_g[tid] = g;
        s_diff[tid][0] = tr1k(x_grid[g * 3 + 0]) - tr1k(src[s * 3 + 0]);
        s_diff[tid][1] = tr1k(x_grid[g * 3 + 1]) - tr1k(src[s * 3 + 1]);
        s_diff[tid][2] = tr1k(x_grid[g * 3 + 2]) - tr1k(src[s * 3 + 2]);
    }
    for (int i = tid; i < NSTA; i += 256) s_sta[i] = sta_ind[i];
    __syncthreads();

    const float mag_s = mag[s];
    const float srcx = src[s * 3 + 0];
    const float srcy = src[s * 3 + 1];
    const float srcz = src[s * 3 + 2];
    const float sp_mc0 = softplus(mag_coef[0]), sp_mc1 = softplus(mag_coef[1]);
    const float sp_ec0 = softplus(epi_coef[0]), sp_ec1 = softplus(epi_coef[1]);
    const float dc0 = dep_coef[0], dc1 = dep_coef[1];

    for (int i = tid; i < NSTA; i += 256) {
        const int st = s_sta[i];
        float wsum = 0.0f, a0 = 0.0f, a1 = 0.0f;
#pragma unroll
        for (int k = 0; k < KK; ++k) {
            const int g = s_g[k];
            const float* kp = coefs_ker + ((size_t)g * L_N + st) * 3;
            float k0 = softplus(kp[0]);
            float k1 = softplus(kp[1]);
            float k2 = softplus(kp[2]);
            float t0 = s_diff[k][0] / k0;
            float t1 = s_diff[k][1] / k1;
            float t2 = s_diff[k][2] / k2;
            float e  = expf(-0.5f * ((t0 * t0 + t1 * t1) + t2 * t2));
            const float* cp = coefs + ((size_t)g * L_N + st) * 2;
            wsum += e;
            a0 += e * cp[0];
            a1 += e * cp[1];
        }
        if (wsum == 0.0f) wsum = 1.0f;

        const int ph = phase[i];
        float bias = ((ph == 0) ? a0 : a1) / wsum;

        float dx = srcx * 1000.0f - sta[i * 3 + 0] * 1000.0f;
        float dy = srcy * 1000.0f - sta[i * 3 + 1] * 1000.0f;
        float lz = log10f(sqrtf(dx * dx + dy * dy) + 1.0f);
        float ld = log10f(fabsf(srcz - sta[i * 3 + 2]) + 1.0f);

        float mc = (ph == 0) ? sp_mc0 : sp_mc1;
        float ec = (ph == 0) ? sp_ec0 : sp_ec1;
        float dc = (ph == 0) ? dc0 : dc1;

        out[(size_t)s * NSTA + i] = mag_s * mc - ec * lz + dc * ld + bias;
    }
}

extern "C" void kernel_launch(void* const* d_in, const int* in_sizes, int n_in,
                              void* d_out, int out_size, void* d_ws, size_t ws_size,
                              hipStream_t stream) {
    const float* sta       = (const float*)d_in[0];
    const float* src       = (const float*)d_in[1];
    const float* mag       = (const float*)d_in[2];
    const int*   phase     = (const int*)d_in[3];
    const float* x_grid    = (const float*)d_in[4];
    const float* locs_ref  = (const float*)d_in[5];
    const float* mag_coef  = (const float*)d_in[6];
    const float* epi_coef  = (const float*)d_in[7];
    const float* dep_coef  = (const float*)d_in[8];
    const float* coefs     = (const float*)d_in[9];
    const float* coefs_ker = (const float*)d_in[10];
    float* out = (float*)d_out;

    const size_t pk_bytes = (size_t)G_N * NSTA * sizeof(uint2);   // 32 MB
    const size_t tail_ints = (size_t)NSRC * KK + NSTA + 3 * G_N + 3 * NSRC;
    const size_t need_fast = pk_bytes + tail_ints * 4;

    if (ws_size >= need_fast) {
        uint2* ws_pk   = (uint2*)d_ws;
        int*   ws_idx  = (int*)((char*)d_ws + pk_bytes);
        int*   ws_sta  = ws_idx + (size_t)NSRC * KK;
        float* ws_tg   = (float*)(ws_sta + NSTA);
        float* ws_ts   = ws_tg + 3 * G_N;

        hipLaunchKernelGGL(sta_prep_kernel, dim3(NSTA), dim3(64), 0, stream,
                           sta, locs_ref, x_grid, src, ws_sta, ws_tg, ws_ts);
        hipLaunchKernelGGL(fused_kernel, dim3(6 * NSRC), dim3(256), 0, stream,
                           coefs, coefs_ker, ws_sta, phase, ws_pk,
                           ws_tg, ws_ts, ws_idx);
        hipLaunchKernelGGL(magnitude_fast_kernel, dim3(NSRC), dim3(256), 0, stream,
                           sta, src, mag, phase, x_grid,
                           mag_coef, epi_coef, dep_coef,
                           ws_pk, ws_idx, out);
    } else {
        int*   ws_sta = (int*)d_ws;
        int*   ws_idx = ws_sta + NSTA;
        float* ws_tg  = (float*)(ws_idx + (size_t)NSRC * KK);
        float* ws_ts  = ws_tg + 3 * G_N;

        hipLaunchKernelGGL(sta_prep_kernel, dim3(NSTA), dim3(64), 0, stream,
                           sta, locs_ref, x_grid, src, ws_sta, ws_tg, ws_ts);
        hipLaunchKernelGGL(topk_only_kernel, dim3(NSRC), dim3(256), 0, stream,
                           ws_tg, ws_ts, ws_idx);
        hipLaunchKernelGGL(magnitude_kernel, dim3(NSRC), dim3(256), 0, stream,
                           sta, src, mag, phase, x_grid,
                           mag_coef, epi_coef, dep_coef,
                           coefs, coefs_ker, ws_sta, ws_idx, out);
    }
}

// Round 9
// 122.043 us; speedup vs baseline: 1.4541x; 1.1193x over previous
//
#include <hip/hip_runtime.h>
#include <hip/hip_fp16.h>
#include <cstddef>

#define G_N   10000
#define L_N   1000
#define NSTA  400
#define NSRC  2000
#define KK    15
#define CAP   512

__device__ __forceinline__ float tr1k(float x) {
    // matches reference: _ftrns(x)/1000.0 = (x*1000.0f)/1000.0f, exact f32 div
    return (x * 1000.0f) / 1000.0f;
}

__device__ __forceinline__ float softplus(float x) {
    return fmaxf(x, 0.0f) + log1pf(expf(-fabsf(x)));
}

__device__ __forceinline__ float softplus_fast(float x) {
    return fmaxf(x, 0.0f) + __logf(1.0f + __expf(-fabsf(x)));
}

__device__ __forceinline__ bool lexless(float v1, int i1, float v2, int i2) {
    return (v1 < v2) || (v1 == v2 && i1 < i2);
}

// ---------------------------------------------------------------------------
// Kernel 1: sta_ind argmin (one wave per station) + tr1k precompute tables
// (tg = tr1k(x_grid), ts = tr1k(src)) + zero used[].
// ---------------------------------------------------------------------------
__global__ void sta_prep_kernel(const float* __restrict__ sta,
                                const float* __restrict__ locs_ref,
                                const float* __restrict__ x_grid,
                                const float* __restrict__ src,
                                int* __restrict__ sta_ind,
                                float* __restrict__ tg,
                                float* __restrict__ ts,
                                int* __restrict__ used) {
#pragma clang fp contract(off)
    const int i    = blockIdx.x;
    const int lane = threadIdx.x;

    const int z = i * 64 + lane;
    for (int p = z; p < 3 * (G_N + NSRC); p += 400 * 64) {
        if (p < 3 * G_N) tg[p] = tr1k(x_grid[p]);
        else             ts[p - 3 * G_N] = tr1k(src[p - 3 * G_N]);
    }
    if (used && z < G_N) used[z] = 0;   // 25600 threads >= G_N

    const float sx = tr1k(sta[i * 3 + 0]);
    const float sy = tr1k(sta[i * 3 + 1]);
    const float sz = tr1k(sta[i * 3 + 2]);
    float best = INFINITY;
    int   bidx = 0x7fffffff;
    for (int j = lane; j < L_N; j += 64) {
        float dx = sx - tr1k(locs_ref[j * 3 + 0]);
        float dy = sy - tr1k(locs_ref[j * 3 + 1]);
        float dz = sz - tr1k(locs_ref[j * 3 + 2]);
        float d  = (dx * dx + dy * dy) + dz * dz;
        if (lexless(d, j, best, bidx)) { best = d; bidx = j; }
    }
    for (int off = 1; off < 64; off <<= 1) {
        float ov = __shfl_xor(best, off);
        int   oi = __shfl_xor(bidx, off);
        if (lexless(ov, oi, best, bidx)) { best = ov; bidx = oi; }
    }
    if (lane == 0) sta_ind[i] = bidx;
}

// ---------------------------------------------------------------------------
// Kernel 2 (v5 standalone): exact threshold select; no divisions (tg/ts
// precomputed), no histogram, no LDS atomics in the hot path, ~5 KB LDS.
// Pass 1: per-thread min over its ~40 strided candidates -> s_min[256].
// Wave 0: T = 15th smallest of the 256 minima (subset order-stat => T >=
//         15th-smallest distance; survivors {d<=T} superset of top-15).
// Pass 2: recompute d (bit-identical), append survivors (~20-60).
// Wave 0: exact lex sort of survivors -> 15 ascending (dq, g); mark used.
// Fallback n>CAP (degenerate ties): exact 15 block-argmin rounds.
// ---------------------------------------------------------------------------
__global__ __launch_bounds__(256, 8) void topk_only_kernel(
    const float* __restrict__ tg, const float* __restrict__ ts,
    int* __restrict__ idx_out, int* __restrict__ used)
{
#pragma clang fp contract(off)
    const int s    = blockIdx.x;
    const int tid  = threadIdx.x;
    const int lane = tid & 63;
    const int wv   = tid >> 6;

    __shared__ float s_min[256];
    __shared__ int   s_cand[CAP];
    __shared__ float s_cd[CAP];
    __shared__ float s_T;
    __shared__ int   s_cnt;
    __shared__ float s_mv[4];
    __shared__ int   s_mi[4];
    __shared__ int   s_ch[KK];

    if (tid == 0) s_cnt = 0;

    const float sx = ts[s * 3 + 0];
    const float sy = ts[s * 3 + 1];
    const float sz = ts[s * 3 + 2];

    // pass 1: per-thread min
    float mymin = INFINITY;
    for (int g = tid; g < G_N; g += 256) {
        float dx = sx - tg[g * 3 + 0];
        float dy = sy - tg[g * 3 + 1];
        float dz = sz - tg[g * 3 + 2];
        float d  = (dx * dx + dy * dy) + dz * dz;
        mymin = fminf(mymin, d);
    }
    s_min[tid] = mymin;
    __syncthreads();

    // wave 0: T = 15th smallest of 256 minima
    if (wv == 0) {
        float m0 = s_min[lane];
        float m1 = s_min[lane + 64];
        float m2 = s_min[lane + 128];
        float m3 = s_min[lane + 192];
        float T = INFINITY;
        for (int r = 0; r < KK; ++r) {
            float lv = m0; int ls = 0;
            if (m1 < lv) { lv = m1; ls = 1; }
            if (m2 < lv) { lv = m2; ls = 2; }
            if (m3 < lv) { lv = m3; ls = 3; }
            float v = lv; int wl = lane;
            for (int off = 1; off < 64; off <<= 1) {
                float ov = __shfl_xor(v, off);
                int   ol = __shfl_xor(wl, off);
                if (ov < v || (ov == v && ol < wl)) { v = ov; wl = ol; }
            }
            T = v;
            if (wl == lane) {
                if (ls == 0) m0 = INFINITY;
                else if (ls == 1) m1 = INFINITY;
                else if (ls == 2) m2 = INFINITY;
                else m3 = INFINITY;
            }
        }
        if (lane == 0) s_T = T;
    }
    __syncthreads();
    const float T = s_T;

    // pass 2: recompute, append survivors
    for (int g = tid; g < G_N; g += 256) {
        float dx = sx - tg[g * 3 + 0];
        float dy = sy - tg[g * 3 + 1];
        float dz = sz - tg[g * 3 + 2];
        float d  = (dx * dx + dy * dy) + dz * dz;
        if (d <= T) {
            int p = atomicAdd(&s_cnt, 1);
            if (p < CAP) { s_cand[p] = g; s_cd[p] = d; }
        }
    }
    __syncthreads();
    const int n = s_cnt;

    if (n <= CAP) {
        if (wv == 0) {
            float vals[KK];
            int   ids[KK];
#pragma unroll
            for (int j = 0; j < KK; ++j) { vals[j] = INFINITY; ids[j] = 0x7fffffff; }
            for (int c = lane; c < n; c += 64) {
                int   g = s_cand[c];
                float d = s_cd[c];
                if (lexless(d, g, vals[KK - 1], ids[KK - 1])) {
                    float cv = d; int ci = g;
#pragma unroll
                    for (int j = 0; j < KK; ++j) {
                        bool sw = lexless(cv, ci, vals[j], ids[j]);
                        float tv = sw ? vals[j] : cv;
                        int   ti = sw ? ids[j]  : ci;
                        vals[j]  = sw ? cv : vals[j];
                        ids[j]   = sw ? ci : ids[j];
                        cv = tv; ci = ti;
                    }
                }
            }
            for (int r = 0; r < KK; ++r) {
                float v  = vals[0];
                int   id = ids[0];
                int   who = lane;
                for (int off = 1; off < 64; off <<= 1) {
                    float ov = __shfl_xor(v, off);
                    int   oi = __shfl_xor(id, off);
                    int   ow = __shfl_xor(who, off);
                    if (lexless(ov, oi, v, id)) { v = ov; id = oi; who = ow; }
                }
                if (lane == 0) {
                    idx_out[s * KK + r] = id;
                    if (used) used[id] = 1;   // benign race; all writers store 1
                }
                if (who == lane) {
#pragma unroll
                    for (int j = 0; j < KK - 1; ++j) { vals[j] = vals[j + 1]; ids[j] = ids[j + 1]; }
                    vals[KK - 1] = INFINITY;
                    ids[KK - 1]  = 0x7fffffff;
                }
            }
        }
    } else {
        // degenerate-ties fallback: exact 15 rounds of block argmin
        for (int r = 0; r < KK; ++r) {
            float v  = INFINITY;
            int   id = 0x7fffffff;
            for (int g = tid; g < G_N; g += 256) {
                bool skip = false;
                for (int j = 0; j < r; ++j) skip = skip || (s_ch[j] == g);
                if (skip) continue;
                float dx = sx - tg[g * 3 + 0];
                float dy = sy - tg[g * 3 + 1];
                float dz = sz - tg[g * 3 + 2];
                float d  = (dx * dx + dy * dy) + dz * dz;
                if (lexless(d, g, v, id)) { v = d; id = g; }
            }
            for (int off = 1; off < 64; off <<= 1) {
                float ov = __shfl_xor(v, off);
                int   oi = __shfl_xor(id, off);
                if (lexless(ov, oi, v, id)) { v = ov; id = oi; }
            }
            if (lane == 0) { s_mv[wv] = v; s_mi[wv] = id; }
            __syncthreads();
            if (tid == 0) {
                float bv = s_mv[0]; int bi = s_mi[0];
                for (int w = 1; w < 4; ++w)
                    if (lexless(s_mv[w], s_mi[w], bv, bi)) { bv = s_mv[w]; bi = s_mi[w]; }
                s_ch[r] = bi;
                idx_out[s * KK + r] = bi;
                if (used) used[bi] = 1;
            }
            __syncthreads();
        }
    }
}

// ---------------------------------------------------------------------------
// Kernel 3: pack (fp16). One block per used g. Stage 20 KB of rows into LDS
// (float4 coalesced), gather 400 station columns, fold fast-softplus
// reciprocal + phase select, write 8 B/station at [g][i].
// ---------------------------------------------------------------------------
__global__ __launch_bounds__(256, 8) void pack_kernel(
    const float* __restrict__ coefs, const float* __restrict__ coefs_ker,
    const int* __restrict__ sta_ind, const int* __restrict__ phase,
    const int* __restrict__ used,
    uint2* __restrict__ pk)
{
    const int g = blockIdx.x;
    if (!used[g]) return;            // wave-uniform early exit
    const int tid = threadIdx.x;

    __shared__ float s_ker[L_N * 3];
    __shared__ float s_c[L_N * 2];

    const float4* kr4 = (const float4*)(coefs_ker + (size_t)g * (L_N * 3)); // 750 vec4
    const float4* cr4 = (const float4*)(coefs     + (size_t)g * (L_N * 2)); // 500 vec4
    float4* sk4 = (float4*)s_ker;
    float4* sc4 = (float4*)s_c;
#pragma unroll
    for (int j = 0; j < 3; ++j) {
        int p = tid + j * 256;
        if (p < (L_N * 3) / 4) sk4[p] = kr4[p];
    }
#pragma unroll
    for (int j = 0; j < 2; ++j) {
        int p = tid + j * 256;
        if (p < (L_N * 2) / 4) sc4[p] = cr4[p];
    }
    const int i1  = tid + 256;
    const int st0 = sta_ind[tid];
    const int ph0 = phase[tid];
    const int st1 = (i1 < NSTA) ? sta_ind[i1] : 0;
    const int ph1 = (i1 < NSTA) ? phase[i1] : 0;
    __syncthreads();

    {
        float rk0 = 1.0f / softplus_fast(s_ker[st0 * 3 + 0]);
        float rk1 = 1.0f / softplus_fast(s_ker[st0 * 3 + 1]);
        float rk2 = 1.0f / softplus_fast(s_ker[st0 * 3 + 2]);
        float c   = (ph0 == 0) ? s_c[st0 * 2 + 0] : s_c[st0 * 2 + 1];
        __half2 a = __floats2half2_rn(rk0, rk1);
        __half2 b = __floats2half2_rn(rk2, c);
        uint2 u;
        u.x = *reinterpret_cast<unsigned int*>(&a);
        u.y = *reinterpret_cast<unsigned int*>(&b);
        pk[(size_t)g * NSTA + tid] = u;
    }
    if (i1 < NSTA) {
        float rk0 = 1.0f / softplus_fast(s_ker[st1 * 3 + 0]);
        float rk1 = 1.0f / softplus_fast(s_ker[st1 * 3 + 1]);
        float rk2 = 1.0f / softplus_fast(s_ker[st1 * 3 + 2]);
        float c   = (ph1 == 0) ? s_c[st1 * 2 + 0] : s_c[st1 * 2 + 1];
        __half2 a = __floats2half2_rn(rk0, rk1);
        __half2 b = __floats2half2_rn(rk2, c);
        uint2 u;
        u.x = *reinterpret_cast<unsigned int*>(&a);
        u.y = *reinterpret_cast<unsigned int*>(&b);
        pk[(size_t)g * NSTA + i1] = u;
    }
}

// ---------------------------------------------------------------------------
// Kernel 4: main fused computation, fast path (fp16 packed table).
// ---------------------------------------------------------------------------
__global__ __launch_bounds__(256, 8) void magnitude_fast_kernel(
    const float* __restrict__ sta, const float* __restrict__ src,
    const float* __restrict__ mag, const int* __restrict__ phase,
    const float* __restrict__ x_grid,
    const float* __restrict__ mag_coef, const float* __restrict__ epi_coef,
    const float* __restrict__ dep_coef,
    const uint2* __restrict__ pk, const int* __restrict__ idx,
    float* __restrict__ out)
{
    const int s   = blockIdx.x;
    const int tid = threadIdx.x;

    __shared__ float s_diff[KK][3];
    __shared__ int   s_g[KK];

    if (tid < KK) {
        int g = idx[s * KK + tid];
        s_g[tid] = g;
        s_diff[tid][0] = tr1k(x_grid[g * 3 + 0]) - tr1k(src[s * 3 + 0]);
        s_diff[tid][1] = tr1k(x_grid[g * 3 + 1]) - tr1k(src[s * 3 + 1]);
        s_diff[tid][2] = tr1k(x_grid[g * 3 + 2]) - tr1k(src[s * 3 + 2]);
    }
    __syncthreads();

    const float mag_s = mag[s];
    const float srcx = src[s * 3 + 0];
    const float srcy = src[s * 3 + 1];
    const float srcz = src[s * 3 + 2];
    const float sp_mc0 = softplus(mag_coef[0]), sp_mc1 = softplus(mag_coef[1]);
    const float sp_ec0 = softplus(epi_coef[0]), sp_ec1 = softplus(epi_coef[1]);
    const float dc0 = dep_coef[0], dc1 = dep_coef[1];

    for (int i = tid; i < NSTA; i += 256) {
        float wsum = 0.0f, a = 0.0f;
#pragma unroll
        for (int k = 0; k < KK; ++k) {
            uint2 u = pk[(size_t)s_g[k] * NSTA + i];
            __half2 h01 = *reinterpret_cast<const __half2*>(&u.x);
            __half2 h23 = *reinterpret_cast<const __half2*>(&u.y);
            float2 f01 = __half22float2(h01);
            float2 f23 = __half22float2(h23);
            float t0 = s_diff[k][0] * f01.x;
            float t1 = s_diff[k][1] * f01.y;
            float t2 = s_diff[k][2] * f23.x;
            float e  = __expf(-0.5f * ((t0 * t0 + t1 * t1) + t2 * t2));
            wsum += e;
            a    += e * f23.y;
        }
        if (wsum == 0.0f) wsum = 1.0f;

        const int ph = phase[i];
        float bias = a / wsum;

        float dx = srcx * 1000.0f - sta[i * 3 + 0] * 1000.0f;
        float dy = srcy * 1000.0f - sta[i * 3 + 1] * 1000.0f;
        float lz = __log10f(__fsqrt_rn(dx * dx + dy * dy) + 1.0f);
        float ld = __log10f(fabsf(srcz - sta[i * 3 + 2]) + 1.0f);

        float mc = (ph == 0) ? sp_mc0 : sp_mc1;
        float ec = (ph == 0) ? sp_ec0 : sp_ec1;
        float dc = (ph == 0) ? dc0 : dc1;

        out[(size_t)s * NSTA + i] = mag_s * mc - ec * lz + dc * ld + bias;
    }
}

// ---------------------------------------------------------------------------
// Fallback main kernel (direct gather) if ws can't hold the packed table.
// ---------------------------------------------------------------------------
__global__ __launch_bounds__(256) void magnitude_kernel(
    const float* __restrict__ sta, const float* __restrict__ src,
    const float* __restrict__ mag, const int* __restrict__ phase,
    const float* __restrict__ x_grid,
    const float* __restrict__ mag_coef, const float* __restrict__ epi_coef,
    const float* __restrict__ dep_coef,
    const float* __restrict__ coefs, const float* __restrict__ coefs_ker,
    const int* __restrict__ sta_ind, const int* __restrict__ idx,
    float* __restrict__ out)
{
    const int s   = blockIdx.x;
    const int tid = threadIdx.x;

    __shared__ float s_diff[KK][3];
    __shared__ int   s_g[KK];
    __shared__ int   s_sta[NSTA];

    if (tid < KK) {
        int g = idx[s * KK + tid];
        s_g[tid] = g;
        s_diff[tid][0] = tr1k(x_grid[g * 3 + 0]) - tr1k(src[s * 3 + 0]);
        s_diff[tid][1] = tr1k(x_grid[g * 3 + 1]) - tr1k(src[s * 3 + 1]);
        s_diff[tid][2] = tr1k(x_grid[g * 3 + 2]) - tr1k(src[s * 3 + 2]);
    }
    for (int i = tid; i < NSTA; i += 256) s_sta[i] = sta_ind[i];
    __syncthreads();

    const float mag_s = mag[s];
    const float srcx = src[s * 3 + 0];
    const float srcy = src[s * 3 + 1];
    const float srcz = src[s * 3 + 2];
    const float sp_mc0 = softplus(mag_coef[0]), sp_mc1 = softplus(mag_coef[1]);
    const float sp_ec0 = softplus(epi_coef[0]), sp_ec1 = softplus(epi_coef[1]);
    const float dc0 = dep_coef[0], dc1 = dep_coef[1];

    for (int i = tid; i < NSTA; i += 256) {
        const int st = s_sta[i];
        float wsum = 0.0f, a0 = 0.0f, a1 = 0.0f;
#pragma unroll
        for (int k = 0; k < KK; ++k) {
            const int g = s_g[k];
            const float* kp = coefs_ker + ((size_t)g * L_N + st) * 3;
            float k0 = softplus(kp[0]);
            float k1 = softplus(kp[1]);
            float k2 = softplus(kp[2]);
            float t0 = s_diff[k][0] / k0;
            float t1 = s_diff[k][1] / k1;
            float t2 = s_diff[k][2] / k2;
            float e  = expf(-0.5f * ((t0 * t0 + t1 * t1) + t2 * t2));
            const float* cp = coefs + ((size_t)g * L_N + st) * 2;
            wsum += e;
            a0 += e * cp[0];
            a1 += e * cp[1];
        }
        if (wsum == 0.0f) wsum = 1.0f;

        const int ph = phase[i];
        float bias = ((ph == 0) ? a0 : a1) / wsum;

        float dx = srcx * 1000.0f - sta[i * 3 + 0] * 1000.0f;
        float dy = srcy * 1000.0f - sta[i * 3 + 1] * 1000.0f;
        float lz = log10f(sqrtf(dx * dx + dy * dy) + 1.0f);
        float ld = log10f(fabsf(srcz - sta[i * 3 + 2]) + 1.0f);

        float mc = (ph == 0) ? sp_mc0 : sp_mc1;
        float ec = (ph == 0) ? sp_ec0 : sp_ec1;
        float dc = (ph == 0) ? dc0 : dc1;

        out[(size_t)s * NSTA + i] = mag_s * mc - ec * lz + dc * ld + bias;
    }
}

extern "C" void kernel_launch(void* const* d_in, const int* in_sizes, int n_in,
                              void* d_out, int out_size, void* d_ws, size_t ws_size,
                              hipStream_t stream) {
    const float* sta       = (const float*)d_in[0];
    const float* src       = (const float*)d_in[1];
    const float* mag       = (const float*)d_in[2];
    const int*   phase     = (const int*)d_in[3];
    const float* x_grid    = (const float*)d_in[4];
    const float* locs_ref  = (const float*)d_in[5];
    const float* mag_coef  = (const float*)d_in[6];
    const float* epi_coef  = (const float*)d_in[7];
    const float* dep_coef  = (const float*)d_in[8];
    const float* coefs     = (const float*)d_in[9];
    const float* coefs_ker = (const float*)d_in[10];
    float* out = (float*)d_out;

    const size_t pk_bytes = (size_t)G_N * NSTA * sizeof(uint2);   // 32 MB
    const size_t tail_ints = (size_t)NSRC * KK + NSTA + G_N + 3 * G_N + 3 * NSRC;
    const size_t need_fast = pk_bytes + tail_ints * 4;

    if (ws_size >= need_fast) {
        uint2* ws_pk   = (uint2*)d_ws;
        int*   ws_idx  = (int*)((char*)d_ws + pk_bytes);
        int*   ws_sta  = ws_idx + (size_t)NSRC * KK;
        int*   ws_used = ws_sta + NSTA;
        float* ws_tg   = (float*)(ws_used + G_N);
        float* ws_ts   = ws_tg + 3 * G_N;

        hipLaunchKernelGGL(sta_prep_kernel, dim3(NSTA), dim3(64), 0, stream,
                           sta, locs_ref, x_grid, src, ws_sta, ws_tg, ws_ts, ws_used);
        hipLaunchKernelGGL(topk_only_kernel, dim3(NSRC), dim3(256), 0, stream,
                           ws_tg, ws_ts, ws_idx, ws_used);
        hipLaunchKernelGGL(pack_kernel, dim3(G_N), dim3(256), 0, stream,
                           coefs, coefs_ker, ws_sta, phase, ws_used, ws_pk);
        hipLaunchKernelGGL(magnitude_fast_kernel, dim3(NSRC), dim3(256), 0, stream,
                           sta, src, mag, phase, x_grid,
                           mag_coef, epi_coef, dep_coef,
                           ws_pk, ws_idx, out);
    } else {
        int*   ws_sta  = (int*)d_ws;
        int*   ws_idx  = ws_sta + NSTA;
        float* ws_tg   = (float*)(ws_idx + (size_t)NSRC * KK);
        float* ws_ts   = ws_tg + 3 * G_N;

        hipLaunchKernelGGL(sta_prep_kernel, dim3(NSTA), dim3(64), 0, stream,
                           sta, locs_ref, x_grid, src, ws_sta, ws_tg, ws_ts, (int*)nullptr);
        hipLaunchKernelGGL(topk_only_kernel, dim3(NSRC), dim3(256), 0, stream,
                           ws_tg, ws_ts, ws_idx, (int*)nullptr);
        hipLaunchKernelGGL(magnitude_kernel, dim3(NSRC), dim3(256), 0, stream,
                           sta, src, mag, phase, x_grid,
                           mag_coef, epi_coef, dep_coef,
                           coefs, coefs_ker, ws_sta, ws_idx, out);
    }
}